// Round 6
// baseline (3199.332 us; speedup 1.0000x reference)
//
#include <hip/hip_runtime.h>
#include <hip/hip_bf16.h>
#include <cstdint>
#include <cstddef>
#include <type_traits>

constexpr int DIN = 64;
constexpr int DE  = 16;
constexpr int H   = 128;
constexpr int L   = 512;
constexpr int PD  = 1152;
constexpr int NAGG = 2048;  // agg/bn-partial stage-1 blocks

using bf16 = __hip_bfloat16;
typedef __attribute__((ext_vector_type(8))) short short8;
typedef __attribute__((ext_vector_type(4))) float float4v;

// ---- bf16 pack/unpack helpers (bf16x2 in a uint) ----
__device__ __forceinline__ float bflo(unsigned u) { return __uint_as_float(u << 16); }
__device__ __forceinline__ float bfhi(unsigned u) { return __uint_as_float(u & 0xffff0000u); }
__device__ __forceinline__ unsigned short f2b(float f) {
  bf16 h = __float2bfloat16(f);
  return *reinterpret_cast<unsigned short*>(&h);
}
__device__ __forceinline__ unsigned pack2(float a, float b) {
  return (unsigned)f2b(a) | ((unsigned)f2b(b) << 16);
}

// ---------------------------------------------------------------- zero fill
__global__ void k_zero_i32(int* p, int n) {
  int i = blockIdx.x * 256 + threadIdx.x;
  if (i < n) p[i] = 0;
}
__global__ void k_zero_f32(float* p, int n) {
  int i = blockIdx.x * 256 + threadIdx.x;
  if (i < n) p[i] = 0.f;
}

// fp32 -> bf16 (2 elements per thread)
__global__ void k_cvt_bf16(const float* __restrict__ in, bf16* __restrict__ out, int npairs) {
  int i = blockIdx.x * 256 + threadIdx.x;
  if (i >= npairs) return;
  float2 v = ((const float2*)in)[i];
  ((unsigned*)out)[i] = pack2(v.x, v.y);
}

// ---------------------------------------------------------------- CSR build
__global__ void k_deg(const int* __restrict__ dst, int* __restrict__ deg, int e) {
  int i = blockIdx.x * 256 + threadIdx.x;
  if (i < e) atomicAdd(&deg[dst[i]], 1);
}

__global__ void k_scan1(const int* __restrict__ deg, int* __restrict__ out,
                        int* __restrict__ bsum, int n) {
  __shared__ int tmp[512];
  int tid = threadIdx.x;
  int i = blockIdx.x * 512 + tid;
  int v = (i < n) ? deg[i] : 0;
  tmp[tid] = v; __syncthreads();
  for (int s = 1; s < 512; s <<= 1) {
    int t = (tid >= s) ? tmp[tid - s] : 0;
    __syncthreads();
    tmp[tid] += t;
    __syncthreads();
  }
  if (i < n) out[i] = tmp[tid] - v;
  if (tid == 511) bsum[blockIdx.x] = tmp[511];
}

__global__ void k_scan2(int* bsum, int nb) {  // nb <= 512
  __shared__ int tmp[512];
  int tid = threadIdx.x;
  int v = (tid < nb) ? bsum[tid] : 0;
  tmp[tid] = v; __syncthreads();
  for (int s = 1; s < 512; s <<= 1) {
    int t = (tid >= s) ? tmp[tid - s] : 0;
    __syncthreads();
    tmp[tid] += t;
    __syncthreads();
  }
  if (tid < nb) bsum[tid] = tmp[tid] - v;
}

__global__ void k_scan3(int* __restrict__ off, const int* __restrict__ bsum,
                        int* __restrict__ cursor, int n, int total) {
  int i = blockIdx.x * 512 + threadIdx.x;
  if (i < n) { int v = off[i] + bsum[blockIdx.x]; off[i] = v; cursor[i] = v; }
  if (i == 0) off[n] = total;
}

__global__ void k_fill(const int* __restrict__ dst, int* __restrict__ cursor,
                       int* __restrict__ eid, int e) {
  int i = blockIdx.x * 256 + threadIdx.x;
  if (i < e) { int slot = atomicAdd(&cursor[dst[i]], 1); eid[slot] = i; }
}

// ---------------------------------------------------------------- weall: all 14 conv edge-weight vectors [14][16]
__global__ void k_weall(const float* __restrict__ gWe, const float* __restrict__ ga_e,
                        const float* __restrict__ eWe1, const float* __restrict__ ea_e1,
                        const float* __restrict__ eWe2, const float* __restrict__ ea_e2,
                        float* __restrict__ weall) {
  int tid = threadIdx.x;
  if (tid >= 14 * 16) return;
  int c = tid >> 4, j = tid & 15;
  float acc = 0.f;
  if (c < 2) {
    for (int k = 0; k < 4; ++k) acc += gWe[(c * 16 + j) * 4 + k] * ga_e[c * 4 + k];
  } else if (c < 8) {
    int i = c - 2;
    for (int k = 0; k < 128; ++k) acc += eWe1[(i * 16 + j) * 128 + k] * ea_e1[i * 128 + k];
  } else {
    int i = c - 8;
    for (int k = 0; k < 128; ++k) acc += eWe2[(i * 16 + j) * 128 + k] * ea_e2[i * 128 + k];
  }
  weall[c * 16 + j] = acc;
}

// ---------------------------------------------------------------- weight repack into MFMA B-frag order (bf16)
__global__ void k_wpackall(const float* __restrict__ eW1, const float* __restrict__ eW2,
                           bf16* __restrict__ Wp1, bf16* __restrict__ Wp2) {
  int tid = blockIdx.x * 256 + threadIdx.x;
  const int L1TOT = 6 * 8192;
  if (tid < L1TOT) {
    int i = tid / 8192, r = tid % 8192;
    int kt = r / 4096, nt = (r / 512) & 7, l = (r / 8) & 63, j = r & 7;
    int k = kt * 32 + (l >> 4) * 8 + j, col = nt * 16 + (l & 15);
    Wp1[tid] = __float2bfloat16(eW1[(size_t)i * 64 * 128 + k * 128 + col]);
  } else {
    int t2 = tid - L1TOT;
    if (t2 >= 6 * 16384) return;
    int i = t2 / 16384, r = t2 % 16384;
    int kt = r / 4096, nt = (r / 512) & 7, l = (r / 8) & 63, j = r & 7;
    int k = kt * 32 + (l >> 4) * 8 + j, col = nt * 16 + (l & 15);
    Wp2[t2] = __float2bfloat16(eW2[(size_t)i * 128 * 128 + k * 128 + col]);
  }
}

// ---------------------------------------------------------------- CSR prep: src/dst in CSR order + all 14 edots
__global__ void k_csrprep(const int* __restrict__ eid, const int* __restrict__ src,
                          const int* __restrict__ dst, const float* __restrict__ eattr,
                          const float* __restrict__ weall, int* __restrict__ src_csr,
                          int* __restrict__ dst_csr, float* __restrict__ edots, int e) {
  __shared__ float w[14 * 16];
  if (threadIdx.x < 14 * 16) w[threadIdx.x] = weall[threadIdx.x];
  __syncthreads();
  int i = blockIdx.x * 256 + threadIdx.x;
  if (i >= e) return;
  int ed = eid[i];
  src_csr[i] = src[ed];
  dst_csr[i] = dst[ed];
  float ea[16];
  const float4* ep = (const float4*)(eattr + (size_t)ed * 16);
#pragma unroll
  for (int q = 0; q < 4; ++q) {
    float4 v = ep[q];
    ea[q * 4] = v.x; ea[q * 4 + 1] = v.y; ea[q * 4 + 2] = v.z; ea[q * 4 + 3] = v.w;
  }
#pragma unroll
  for (int c = 0; c < 14; ++c) {
    float acc = 0.f;
#pragma unroll
    for (int j = 0; j < 16; ++j) acc += ea[j] * w[c * 16 + j];
    edots[(size_t)c * e + i] = acc;
  }
}

// ---------------------------------------------------------------- MFMA GEMM: out[N,128](bf16) = A[N,K](bf16) @ W(packed)
// BN=true: apply BN1(scale/shift from partial-reduced stats) + leaky(0.01) to A during staging.
// Also fuses s[n] = out_row . a_s, d[n] = out_row . a_d
template <int K, bool BN>
__global__ __launch_bounds__(256) void k_mfma_gemm(
    const bf16* __restrict__ A, const bf16* __restrict__ Wp,
    const float* __restrict__ a_s, const float* __restrict__ a_d,
    bf16* __restrict__ out, float* __restrict__ s, float* __restrict__ d, int n,
    const float* __restrict__ bnsums, const float* __restrict__ bng,
    const float* __restrict__ bnb, float invn) {
  constexpr int KT = K / 32;
  __shared__ bf16 At[64][K + 8];
  __shared__ float sscale[128], sshift[128];
  if (BN) {
    if (threadIdx.x < K) {
      int c = threadIdx.x;
      float mu = bnsums[c] * invn;
      float var = bnsums[128 + c] * invn - mu * mu;
      float sc = rsqrtf(var + 1e-5f) * bng[c];
      sscale[c] = sc;
      sshift[c] = bnb[c] - mu * sc;
    }
    __syncthreads();
  }
  int row0 = blockIdx.x * 64;
  const int vecPerRow = K / 8;
  for (int idx = threadIdx.x; idx < 64 * vecPerRow; idx += 256) {
    int r = idx / vecPerRow, v = idx - r * vecPerRow;
    int gr = row0 + r;
    uint4 u = {0u, 0u, 0u, 0u};
    if (gr < n) u = ((const uint4*)(A + (size_t)gr * K))[v];
    if (BN) {
      float f[8] = {bflo(u.x), bfhi(u.x), bflo(u.y), bfhi(u.y),
                    bflo(u.z), bfhi(u.z), bflo(u.w), bfhi(u.w)};
      int c0 = v * 8;
#pragma unroll
      for (int j = 0; j < 8; ++j) {
        float y = f[j] * sscale[c0 + j] + sshift[c0 + j];
        f[j] = (y > 0.f) ? y : 0.01f * y;
      }
      u.x = pack2(f[0], f[1]); u.y = pack2(f[2], f[3]);
      u.z = pack2(f[4], f[5]); u.w = pack2(f[6], f[7]);
    }
    *((uint4*)&At[r][v * 8]) = u;
  }
  __syncthreads();
  int lane = threadIdx.x & 63, w = threadIdx.x >> 6;
  int c = lane & 15, q = lane >> 4;
  int wrow = w * 16;
  short8 afrag[KT];
#pragma unroll
  for (int kt = 0; kt < KT; ++kt)
    afrag[kt] = *(const short8*)&At[wrow + c][kt * 32 + q * 8];
  const short8* wp8 = (const short8*)Wp;
  float4v acc[8];
#pragma unroll
  for (int nt = 0; nt < 8; ++nt) acc[nt] = {0.f, 0.f, 0.f, 0.f};
#pragma unroll
  for (int kt = 0; kt < KT; ++kt) {
#pragma unroll
    for (int nt = 0; nt < 8; ++nt) {
      short8 bfrag = wp8[(kt * 8 + nt) * 64 + lane];
      acc[nt] = __builtin_amdgcn_mfma_f32_16x16x32_bf16(afrag[kt], bfrag, acc[nt], 0, 0, 0);
    }
  }
#pragma unroll
  for (int nt = 0; nt < 8; ++nt) {
#pragma unroll
    for (int reg = 0; reg < 4; ++reg) {
      int gr = row0 + wrow + q * 4 + reg;
      if (gr < n) out[(size_t)gr * 128 + nt * 16 + c] = __float2bfloat16(acc[nt][reg]);
    }
  }
#pragma unroll
  for (int reg = 0; reg < 4; ++reg) {
    float vs = 0.f, vd = 0.f;
#pragma unroll
    for (int nt = 0; nt < 8; ++nt) {
      float y = acc[nt][reg];
      int col = nt * 16 + c;
      vs += y * a_s[col];
      vd += y * a_d[col];
    }
#pragma unroll
    for (int o = 1; o < 16; o <<= 1) { vs += __shfl_xor(vs, o); vd += __shfl_xor(vd, o); }
    int gr = row0 + wrow + q * 4 + reg;
    if (c == 0 && gr < n) { s[gr] = vs; d[gr] = vd; }
  }
}

// ---------------------------------------------------------------- edge logits in CSR order
__global__ void k_edge_l(const int* __restrict__ src_csr, const int* __restrict__ dst_csr,
                         const float* __restrict__ edot, const float* __restrict__ s,
                         const float* __restrict__ d, float* __restrict__ lcsr, int e) {
  int i = blockIdx.x * 256 + threadIdx.x;
  if (i >= e) return;
  float l = s[src_csr[i]] + d[dst_csr[i]] + edot[i];
  lcsr[i] = (l > 0.f) ? l : 0.2f * l;
}

// ---------------------------------------------------------------- agg + fused BN partial stats
// one wave per node; lanes = 4 edge slots (g) x 16 channel groups (h, 8ch each).
// grid-stride over nodes; per-block partial sum/sumsq written to partials[block][256].
__global__ __launch_bounds__(256) void k_agg128s(
    const int* __restrict__ off, const int* __restrict__ src_csr,
    const float* __restrict__ lcsr, const bf16* __restrict__ feat,
    const float* __restrict__ bias, bf16* __restrict__ out,
    float* __restrict__ partials, int n) {
  __shared__ float sm[4][128], sq[4][128];
  int w = threadIdx.x >> 6, lane = threadIdx.x & 63;
  int g = lane >> 4, h = lane & 15;
  float b8[8];
#pragma unroll
  for (int j = 0; j < 8; ++j) b8[j] = bias[h * 8 + j];
  float sum8[8], sq8[8];
#pragma unroll
  for (int j = 0; j < 8; ++j) { sum8[j] = 0.f; sq8[j] = 0.f; }
  int stride = gridDim.x * 4;
  for (int node = blockIdx.x * 4 + w; node < n; node += stride) {
    int e0 = off[node], e1 = off[node + 1];
    float m = -INFINITY;
    for (int i = e0 + lane; i < e1; i += 64) m = fmaxf(m, lcsr[i]);
#pragma unroll
    for (int o = 32; o; o >>= 1) m = fmaxf(m, __shfl_xor(m, o));
    float den = 0.f;
    for (int i = e0 + lane; i < e1; i += 64) den += __expf(lcsr[i] - m);
#pragma unroll
    for (int o = 32; o; o >>= 1) den += __shfl_xor(den, o);
    float inv = 1.f / (den + 1e-16f);
    float acc[8];
#pragma unroll
    for (int j = 0; j < 8; ++j) acc[j] = 0.f;
    for (int i = e0 + g; i < e1; i += 4) {
      float alpha = __expf(lcsr[i] - m) * inv;
      uint4 u = ((const uint4*)(feat + (size_t)src_csr[i] * 128))[h];
      acc[0] += alpha * bflo(u.x); acc[1] += alpha * bfhi(u.x);
      acc[2] += alpha * bflo(u.y); acc[3] += alpha * bfhi(u.y);
      acc[4] += alpha * bflo(u.z); acc[5] += alpha * bfhi(u.z);
      acc[6] += alpha * bflo(u.w); acc[7] += alpha * bfhi(u.w);
    }
#pragma unroll
    for (int j = 0; j < 8; ++j) {
      acc[j] += __shfl_xor(acc[j], 16);
      acc[j] += __shfl_xor(acc[j], 32);
      acc[j] += b8[j];
    }
    if (g == 0) {
      uint4 o4;
      o4.x = pack2(acc[0], acc[1]); o4.y = pack2(acc[2], acc[3]);
      o4.z = pack2(acc[4], acc[5]); o4.w = pack2(acc[6], acc[7]);
      ((uint4*)(out + (size_t)node * 128))[h] = o4;
#pragma unroll
      for (int j = 0; j < 8; ++j) { sum8[j] += acc[j]; sq8[j] += acc[j] * acc[j]; }
    }
  }
  if (g == 0) {
#pragma unroll
    for (int j = 0; j < 8; ++j) { sm[w][h * 8 + j] = sum8[j]; sq[w][h * 8 + j] = sq8[j]; }
  }
  __syncthreads();
  if (threadIdx.x < 128) {
    int c = threadIdx.x;
    float a = sm[0][c] + sm[1][c] + sm[2][c] + sm[3][c];
    float b = sq[0][c] + sq[1][c] + sq[2][c] + sq[3][c];
    partials[(size_t)blockIdx.x * 256 + c] = a;
    partials[(size_t)blockIdx.x * 256 + 128 + c] = b;
  }
}

// ---------------------------------------------------------------- gate feature + s/d
__global__ void k_gfeat(const float* __restrict__ x, const float* __restrict__ W,
                        const float* __restrict__ a_s, const float* __restrict__ a_d,
                        float* __restrict__ gfeat, float* __restrict__ s,
                        float* __restrict__ d, int n) {
  int i = blockIdx.x * 256 + threadIdx.x;
  if (i >= n) return;
  const float* xr = x + (size_t)i * DIN;
  float acc[4] = {0.f, 0.f, 0.f, 0.f};
  for (int k = 0; k < DIN; ++k) {
    float xv = xr[k];
#pragma unroll
    for (int j = 0; j < 4; ++j) acc[j] += xv * W[k * 4 + j];
  }
  float ss = 0.f, dd = 0.f;
#pragma unroll
  for (int j = 0; j < 4; ++j) {
    gfeat[(size_t)i * 4 + j] = acc[j];
    ss += acc[j] * a_s[j];
    dd += acc[j] * a_d[j];
  }
  s[i] = ss; d[i] = dd;
}

// ---------------------------------------------------------------- gate aggregation + channel softmax
__global__ void k_agg4(const int* __restrict__ off, const int* __restrict__ src_csr,
                       const float* __restrict__ lcsr, const float* __restrict__ gfeat,
                       const float* __restrict__ bias, float* __restrict__ gates, int n) {
  int node = blockIdx.x * 256 + threadIdx.x;
  if (node >= n) return;
  int e0 = off[node], e1 = off[node + 1];
  float m = -INFINITY;
  for (int i = e0; i < e1; ++i) m = fmaxf(m, lcsr[i]);
  float den = 0.f;
  for (int i = e0; i < e1; ++i) den += __expf(lcsr[i] - m);
  float inv = 1.f / (den + 1e-16f);
  float4 acc = {0.f, 0.f, 0.f, 0.f};
  for (int i = e0; i < e1; ++i) {
    float a = __expf(lcsr[i] - m) * inv;
    float4 fr = *((const float4*)(gfeat + (size_t)src_csr[i] * 4));
    acc.x += a * fr.x; acc.y += a * fr.y; acc.z += a * fr.z; acc.w += a * fr.w;
  }
  float b0 = bias[0], b1 = bias[1], b2 = bias[2], b3 = bias[3];
  acc.x += b0; acc.y += b1; acc.z += b2; acc.w += b3;
  float mm = fmaxf(fmaxf(acc.x, acc.y), fmaxf(acc.z, acc.w));
  float e0s = __expf(acc.x - mm), e1s = __expf(acc.y - mm);
  float e2s = __expf(acc.z - mm), e3s = __expf(acc.w - mm);
  float is = 1.f / (e0s + e1s + e2s + e3s);
  float4 g4 = {e0s * is, e1s * is, e2s * is, e3s * is};
  *((float4*)(gates + (size_t)node * 4)) = g4;
}

// stage 2: reduce partials -> sums[0..127], sums[128..255]. grid = 16 blocks x 8 ch.
__global__ void k_bnstats_fin(const float* __restrict__ partials, float* __restrict__ sums,
                              int nblk) {
  int t = threadIdx.x;
  int cl = t >> 5, sl = t & 31;
  int ch = blockIdx.x * 8 + cl;
  float a = 0.f, b = 0.f;
  for (int blk = sl; blk < nblk; blk += 32) {
    a += partials[(size_t)blk * 256 + ch];
    b += partials[(size_t)blk * 256 + 128 + ch];
  }
#pragma unroll
  for (int o = 16; o; o >>= 1) { a += __shfl_xor(a, o); b += __shfl_xor(b, o); }
  if (sl == 0) { sums[ch] = a; sums[128 + ch] = b; }
}

// BN stats fp32 (head path, tiny)
__global__ void k_bnstats_f32(const float* __restrict__ x, float* __restrict__ sums,
                              float* __restrict__ sumsq, int n) {
  __shared__ float s1[256], s2[256];
  int c = threadIdx.x & 127, half = threadIdx.x >> 7;
  float a = 0.f, b = 0.f;
  for (int r = blockIdx.x * 2 + half; r < n; r += gridDim.x * 2) {
    float v = x[(size_t)r * 128 + c];
    a += v; b += v * v;
  }
  s1[threadIdx.x] = a; s2[threadIdx.x] = b;
  __syncthreads();
  if (half == 0) {
    atomicAdd(&sums[c], s1[c] + s1[c + 128]);
    atomicAdd(&sumsq[c], s2[c] + s2[c + 128]);
  }
}

// ---------------------------------------------------------------- fused BN2+leaky+gate+pool
__global__ void k_poolexpert(const bf16* __restrict__ x, const float* __restrict__ sums,
                             const float* __restrict__ sumsq, const float* __restrict__ g,
                             const float* __restrict__ bb, const int* __restrict__ batch,
                             const float* __restrict__ gates0, int slot0,
                             const float* __restrict__ gates1, int slot1,
                             float* __restrict__ pooled0, float* __restrict__ pooled1,
                             int n, float invn) {
  int b = blockIdx.x, t = threadIdx.x;
  int lo = 0, hi = n;
  while (lo < hi) { int m = (lo + hi) >> 1; if (batch[m] < b) lo = m + 1; else hi = m; }
  int start = lo;
  lo = start; hi = n;
  while (lo < hi) { int m = (lo + hi) >> 1; if (batch[m] < b + 1) lo = m + 1; else hi = m; }
  int end = lo;
  int c0 = 2 * t, c1 = 2 * t + 1;
  float mu0 = sums[c0] * invn, mu1 = sums[c1] * invn;
  float sc0 = rsqrtf(sumsq[c0] * invn - mu0 * mu0 + 1e-5f) * g[c0];
  float sc1 = rsqrtf(sumsq[c1] * invn - mu1 * mu1 + 1e-5f) * g[c1];
  float sh0 = bb[c0], sh1 = bb[c1];
  float a00 = 0.f, a01 = 0.f, a10 = 0.f, a11 = 0.f;
  for (int r = start; r < end; ++r) {
    unsigned u = ((const unsigned*)(x + (size_t)r * 128))[t];
    float y0 = (bflo(u) - mu0) * sc0 + sh0;
    float y1 = (bfhi(u) - mu1) * sc1 + sh1;
    y0 = (y0 > 0.f) ? y0 : 0.01f * y0;
    y1 = (y1 > 0.f) ? y1 : 0.01f * y1;
    if (slot0 >= 0) {
      float gw = gates0[(size_t)r * 4 + slot0];
      a00 += gw * y0; a01 += gw * y1;
    }
    if (slot1 >= 0) {
      float gw = gates1[(size_t)r * 4 + slot1];
      a10 += gw * y0; a11 += gw * y1;
    }
  }
  if (slot0 >= 0) {
    pooled0[(size_t)b * 128 + c0] += a00;
    pooled0[(size_t)b * 128 + c1] += a01;
  }
  if (slot1 >= 0) {
    pooled1[(size_t)b * 128 + c0] += a10;
    pooled1[(size_t)b * 128 + c1] += a11;
  }
}

// ---------------------------------------------------------------- K^T = (pe@Wk)^T [128][L], V = pe@Wv [L][128]
__global__ void k_kv(const float* __restrict__ pe, const float* __restrict__ Wk,
                     const float* __restrict__ Wv, float* __restrict__ Kt,
                     float* __restrict__ Vout) {
  __shared__ float per[PD];
  int l = blockIdx.x, c = threadIdx.x;
  for (int p = threadIdx.x; p < PD; p += 128) per[p] = pe[(size_t)l * PD + p];
  __syncthreads();
  float ak = 0.f, av = 0.f;
  for (int p = 0; p < PD; ++p) {
    float v = per[p];
    ak += v * Wk[p * 128 + c];
    av += v * Wv[p * 128 + c];
  }
  Kt[(size_t)c * L + l] = ak;
  Vout[(size_t)l * 128 + c] = av;
}

// out[row,:] = in[row,:Kdim] @ W[Kdim,128]
__global__ void k_rowgemm(const float* __restrict__ in, const float* __restrict__ W,
                          float* __restrict__ out, int Kdim) {
  __shared__ float rr[256];
  int row = blockIdx.x, c = threadIdx.x;
  for (int k = threadIdx.x; k < Kdim; k += 128) rr[k] = in[(size_t)row * Kdim + k];
  __syncthreads();
  float acc = 0.f;
  for (int k = 0; k < Kdim; ++k) acc += rr[k] * W[k * 128 + c];
  out[(size_t)row * 128 + c] = acc;
}

// ---------------------------------------------------------------- cross-attention, 4 graphs per block
__global__ void k_attn(const float* __restrict__ Q, const float* __restrict__ Kt,
                       const float* __restrict__ Vm, float* __restrict__ ctx) {
  __shared__ float q[4][128];
  __shared__ float sc[4][L];
  __shared__ float4 red[128];
  __shared__ float4 Mg, Ig;
  int b0 = blockIdx.x * 4, t = threadIdx.x;
#pragma unroll
  for (int g = 0; g < 4; ++g) q[g][t] = Q[(size_t)(b0 + g) * 128 + t];
  __syncthreads();
  float acc[4][4];
#pragma unroll
  for (int g = 0; g < 4; ++g)
#pragma unroll
    for (int j = 0; j < 4; ++j) acc[g][j] = 0.f;
  for (int k = 0; k < 128; ++k) {
    const float* kr = Kt + (size_t)k * L + t;
    float k0 = kr[0], k1 = kr[128], k2 = kr[256], k3 = kr[384];
#pragma unroll
    for (int g = 0; g < 4; ++g) {
      float qv = q[g][k];
      acc[g][0] += qv * k0; acc[g][1] += qv * k1;
      acc[g][2] += qv * k2; acc[g][3] += qv * k3;
    }
  }
  const float scale = 0.08838834764831845f;
  float4 pm;
  {
    float m[4];
#pragma unroll
    for (int g = 0; g < 4; ++g) {
#pragma unroll
      for (int j = 0; j < 4; ++j) {
        acc[g][j] *= scale;
        sc[g][t + j * 128] = acc[g][j];
      }
      m[g] = fmaxf(fmaxf(acc[g][0], acc[g][1]), fmaxf(acc[g][2], acc[g][3]));
    }
    pm = {m[0], m[1], m[2], m[3]};
  }
  red[t] = pm; __syncthreads();
  for (int s = 64; s > 0; s >>= 1) {
    if (t < s) {
      float4 o = red[t + s];
      red[t].x = fmaxf(red[t].x, o.x); red[t].y = fmaxf(red[t].y, o.y);
      red[t].z = fmaxf(red[t].z, o.z); red[t].w = fmaxf(red[t].w, o.w);
    }
    __syncthreads();
  }
  if (t == 0) Mg = red[0];
  __syncthreads();
  float4 M = Mg;
  float4 ps = {0, 0, 0, 0};
#pragma unroll
  for (int g = 0; g < 4; ++g) {
    float mg = (g == 0) ? M.x : (g == 1) ? M.y : (g == 2) ? M.z : M.w;
    float sgsum = 0.f;
#pragma unroll
    for (int j = 0; j < 4; ++j) {
      float e = __expf(acc[g][j] - mg);
      sc[g][t + j * 128] = e;
      sgsum += e;
    }
    if (g == 0) ps.x = sgsum; else if (g == 1) ps.y = sgsum;
    else if (g == 2) ps.z = sgsum; else ps.w = sgsum;
  }
  __syncthreads();
  red[t] = ps; __syncthreads();
  for (int s = 64; s > 0; s >>= 1) {
    if (t < s) {
      float4 o = red[t + s];
      red[t].x += o.x; red[t].y += o.y; red[t].z += o.z; red[t].w += o.w;
    }
    __syncthreads();
  }
  if (t == 0) Ig = {1.f / red[0].x, 1.f / red[0].y, 1.f / red[0].z, 1.f / red[0].w};
  __syncthreads();
  float4 I = Ig;
  float o0 = 0.f, o1 = 0.f, o2 = 0.f, o3 = 0.f;
  for (int l = 0; l < L; ++l) {
    float v = Vm[(size_t)l * 128 + t];
    o0 += sc[0][l] * v; o1 += sc[1][l] * v; o2 += sc[2][l] * v; o3 += sc[3][l] * v;
  }
  ctx[(size_t)(b0 + 0) * 128 + t] = o0 * I.x;
  ctx[(size_t)(b0 + 1) * 128 + t] = o1 * I.y;
  ctx[(size_t)(b0 + 2) * 128 + t] = o2 * I.z;
  ctx[(size_t)(b0 + 3) * 128 + t] = o3 * I.w;
}

// hh = concat(pooled, ctx) @ Wh1 + bh1
__global__ void k_head1(const float* __restrict__ pooled, const float* __restrict__ ctx,
                        const float* __restrict__ Wh1, const float* __restrict__ bh1,
                        float* __restrict__ hh) {
  __shared__ float f[256];
  int b = blockIdx.x, c = threadIdx.x;
  f[c] = pooled[(size_t)b * 128 + c];
  f[c + 128] = ctx[(size_t)b * 128 + c];
  __syncthreads();
  float acc = bh1[c];
  for (int k = 0; k < 256; ++k) acc += f[k] * Wh1[k * 128 + c];
  hh[(size_t)b * 128 + c] = acc;
}

// bn + leaky + final dot with Wh2 -> out[b*2+t]
__global__ void k_head2(const float* __restrict__ hh, const float* __restrict__ sums,
                        const float* __restrict__ sumsq, const float* __restrict__ g,
                        const float* __restrict__ bbn, const float* __restrict__ Wh2,
                        const float* __restrict__ bh2, float* __restrict__ out, int t,
                        float invn) {
  __shared__ float red[2];
  int b = blockIdx.x, c = threadIdx.x;
  float mu = sums[c] * invn;
  float var = sumsq[c] * invn - mu * mu;
  float y = (hh[(size_t)b * 128 + c] - mu) * rsqrtf(var + 1e-5f) * g[c] + bbn[c];
  y = (y > 0.f) ? y : 0.01f * y;
  float p = y * Wh2[c];
  for (int o = 32; o; o >>= 1) p += __shfl_down(p, o);
  if ((threadIdx.x & 63) == 0) red[threadIdx.x >> 6] = p;
  __syncthreads();
  if (threadIdx.x == 0) out[(size_t)b * 2 + t] = red[0] + red[1] + bh2[0];
}

extern "C" void kernel_launch(void* const* d_in, const int* in_sizes, int n_in,
                              void* d_out, int out_size, void* d_ws, size_t ws_size,
                              hipStream_t stream) {
  (void)n_in; (void)ws_size;
  const float* x     = (const float*)d_in[0];
  const int*   eidx  = (const int*)d_in[1];
  const float* eattr = (const float*)d_in[2];
  const int*   batch = (const int*)d_in[3];
  const float* eW1   = (const float*)d_in[4];
  const float* ea_s1 = (const float*)d_in[5];
  const float* ea_d1 = (const float*)d_in[6];
  const float* eWe1  = (const float*)d_in[7];
  const float* ea_e1 = (const float*)d_in[8];
  const float* eb1   = (const float*)d_in[9];
  const float* bn1_g = (const float*)d_in[10];
  const float* bn1_b = (const float*)d_in[11];
  const float* eW2   = (const float*)d_in[12];
  const float* ea_s2 = (const float*)d_in[13];
  const float* ea_d2 = (const float*)d_in[14];
  const float* eWe2  = (const float*)d_in[15];
  const float* ea_e2 = (const float*)d_in[16];
  const float* eb2   = (const float*)d_in[17];
  const float* bn2_g = (const float*)d_in[18];
  const float* bn2_b = (const float*)d_in[19];
  const float* gW    = (const float*)d_in[20];
  const float* ga_s  = (const float*)d_in[21];
  const float* ga_d  = (const float*)d_in[22];
  const float* gWe   = (const float*)d_in[23];
  const float* ga_e  = (const float*)d_in[24];
  const float* gb    = (const float*)d_in[25];
  const float* Wq    = (const float*)d_in[26];
  const float* Wk    = (const float*)d_in[27];
  const float* Wv    = (const float*)d_in[28];
  const float* pe    = (const float*)d_in[29];
  const float* Wh1   = (const float*)d_in[30];
  const float* bh1   = (const float*)d_in[31];
  const float* hbn_g = (const float*)d_in[32];
  const float* hbn_b = (const float*)d_in[33];
  const float* Wh2   = (const float*)d_in[34];
  const float* bh2   = (const float*)d_in[35];
  float* out = (float*)d_out;

  const int n = in_sizes[0] / DIN;    // 200000
  const int e = in_sizes[1] / 2;      // 800000
  const int nb_graphs = out_size / 2; // 4096
  const int* src = eidx;
  const int* dst = eidx + e;

  char* p = (char*)d_ws;
  auto carve = [&](size_t bytes) {
    void* r = (void*)p;
    p += (bytes + 255) & ~(size_t)255;
    return r;
  };
  int* deg       = (int*)carve((size_t)n * 4);
  int* off       = (int*)carve(((size_t)n + 1) * 4);
  int* cursor    = (int*)carve((size_t)n * 4);
  int* eid       = (int*)carve((size_t)e * 4);
  int* bsum      = (int*)carve(4096);
  int* src_csr   = (int*)carve((size_t)e * 4);
  int* dst_csr   = (int*)carve((size_t)e * 4);
  float* edots   = (float*)carve((size_t)14 * e * 4);
  float* weall   = (float*)carve(14 * 16 * 4);
  float* s_arr   = (float*)carve((size_t)n * 4);
  float* d_arr   = (float*)carve((size_t)n * 4);
  float* lcsr    = (float*)carve((size_t)e * 4);
  float* sums    = (float*)carve(256 * 4);
  float* partials = (float*)carve((size_t)NAGG * 256 * 4);
  float* gates0  = (float*)carve((size_t)n * 16);
  float* gates1  = (float*)carve((size_t)n * 16);
  float* gfeat   = (float*)carve((size_t)n * 16);
  float* pooled0 = (float*)carve((size_t)nb_graphs * H * 4);
  float* pooled1 = (float*)carve((size_t)nb_graphs * H * 4);
  float* Ktbuf   = (float*)carve((size_t)L * H * 4);
  float* Vbuf    = (float*)carve((size_t)L * H * 4);
  float* Qbuf    = (float*)carve((size_t)nb_graphs * H * 4);
  float* ctxb    = (float*)carve((size_t)nb_graphs * H * 4);
  float* hhb     = (float*)carve((size_t)nb_graphs * H * 4);
  bf16* featbuf  = (bf16*)carve((size_t)n * H * 2);
  bf16* buf1     = (bf16*)carve((size_t)n * H * 2);
  bf16* xbf      = (bf16*)carve((size_t)n * DIN * 2);
  bf16* Wp1      = (bf16*)carve((size_t)6 * 8192 * 2);
  bf16* Wp2      = (bf16*)carve((size_t)6 * 16384 * 2);

  float invn = 1.0f / n;

  // ---- one-time prep: x->bf16, weight repack
  k_cvt_bf16<<<(n * DIN / 2 + 255) / 256, 256, 0, stream>>>(x, xbf, n * DIN / 2);
  k_wpackall<<<(6 * 8192 + 6 * 16384 + 255) / 256, 256, 0, stream>>>(eW1, eW2, Wp1, Wp2);

  // ---- CSR by dst (reused by all 14 GAT convs)
  k_zero_i32<<<(n + 255) / 256, 256, 0, stream>>>(deg, n);
  k_deg<<<(e + 255) / 256, 256, 0, stream>>>(dst, deg, e);
  int nsb = (n + 511) / 512;
  k_scan1<<<nsb, 512, 0, stream>>>(deg, off, bsum, n);
  k_scan2<<<1, 512, 0, stream>>>(bsum, nsb);
  k_scan3<<<nsb, 512, 0, stream>>>(off, bsum, cursor, n, e);
  k_fill<<<(e + 255) / 256, 256, 0, stream>>>(dst, cursor, eid, e);

  // ---- all 14 edge-weight dots in CSR order
  k_weall<<<1, 256, 0, stream>>>(gWe, ga_e, eWe1, ea_e1, eWe2, ea_e2, weall);
  k_csrprep<<<(e + 255) / 256, 256, 0, stream>>>(eid, src, dst, eattr, weall, src_csr,
                                                 dst_csr, edots, e);

  // ---- gates (2 tasks)
  for (int t = 0; t < 2; ++t) {
    float* gates = t ? gates1 : gates0;
    k_gfeat<<<(n + 255) / 256, 256, 0, stream>>>(x, gW + t * DIN * 4, ga_s + t * 4,
                                                 ga_d + t * 4, gfeat, s_arr, d_arr, n);
    k_edge_l<<<(e + 255) / 256, 256, 0, stream>>>(src_csr, dst_csr, edots + (size_t)t * e,
                                                  s_arr, d_arr, lcsr, e);
    k_agg4<<<(n + 255) / 256, 256, 0, stream>>>(off, src_csr, lcsr, gfeat, gb + t * 4,
                                                gates, n);
  }

  // ---- zero pooled accumulators
  k_zero_f32<<<(nb_graphs * H + 255) / 256, 256, 0, stream>>>(pooled0, nb_graphs * H);
  k_zero_f32<<<(nb_graphs * H + 255) / 256, 256, 0, stream>>>(pooled1, nb_graphs * H);

  // ---- 6 experts (MFMA GEMMs; BN1 fused into layer-2 staging; agg fuses BN partials)
  int gblk = (n + 63) / 64;
  for (int i = 0; i < 6; ++i) {
    // layer 1 (DIN -> H)
    k_mfma_gemm<DIN, false><<<gblk, 256, 0, stream>>>(
        xbf, Wp1 + (size_t)i * 8192, ea_s1 + i * H, ea_d1 + i * H, featbuf, s_arr, d_arr,
        n, nullptr, nullptr, nullptr, 0.f);
    k_edge_l<<<(e + 255) / 256, 256, 0, stream>>>(src_csr, dst_csr,
                                                  edots + (size_t)(2 + i) * e, s_arr,
                                                  d_arr, lcsr, e);
    k_agg128s<<<NAGG, 256, 0, stream>>>(off, src_csr, lcsr, featbuf, eb1 + i * H, buf1,
                                        partials, n);
    k_bnstats_fin<<<16, 256, 0, stream>>>(partials, sums, NAGG);
    // layer 2 (H -> H); BN1 + leaky applied during A staging
    k_mfma_gemm<H, true><<<gblk, 256, 0, stream>>>(
        buf1, Wp2 + (size_t)i * 16384, ea_s2 + i * H, ea_d2 + i * H, featbuf, s_arr,
        d_arr, n, sums, bn1_g + i * H, bn1_b + i * H, invn);
    k_edge_l<<<(e + 255) / 256, 256, 0, stream>>>(src_csr, dst_csr,
                                                  edots + (size_t)(8 + i) * e, s_arr,
                                                  d_arr, lcsr, e);
    k_agg128s<<<NAGG, 256, 0, stream>>>(off, src_csr, lcsr, featbuf, eb2 + i * H, buf1,
                                        partials, n);
    k_bnstats_fin<<<16, 256, 0, stream>>>(partials, sums, NAGG);
    int s0 = (i < 4) ? i : -1;
    int s1 = (i < 2) ? i : (i >= 4 ? i - 2 : -1);
    k_poolexpert<<<nb_graphs, 64, 0, stream>>>(buf1, sums, sums + 128, bn2_g + i * H,
                                               bn2_b + i * H, batch, gates0, s0, gates1,
                                               s1, pooled0, pooled1, n, invn);
  }

  // ---- heads
  for (int t = 0; t < 2; ++t) {
    const float* pooled = t ? pooled1 : pooled0;
    k_kv<<<L, 128, 0, stream>>>(pe + (size_t)t * L * PD, Wk + t * PD * H, Wv + t * PD * H,
                                Ktbuf, Vbuf);
    k_rowgemm<<<nb_graphs, 128, 0, stream>>>(pooled, Wq + t * H * H, Qbuf, H);
    k_attn<<<nb_graphs / 4, 128, 0, stream>>>(Qbuf, Ktbuf, Vbuf, ctxb);
    k_head1<<<nb_graphs, 128, 0, stream>>>(pooled, ctxb, Wh1 + t * 2 * H * H, bh1 + t * H,
                                           hhb);
    k_zero_f32<<<1, 256, 0, stream>>>(sums, 256);
    k_bnstats_f32<<<64, 256, 0, stream>>>(hhb, sums, sums + 128, nb_graphs);
    k_head2<<<nb_graphs, 128, 0, stream>>>(hhb, sums, sums + 128, hbn_g + t * H,
                                           hbn_b + t * H, Wh2 + t * H, bh2 + t, out, t,
                                           1.0f / nb_graphs);
  }
}

// Round 7
// 2894.724 us; speedup vs baseline: 1.1052x; 1.1052x over previous
//
#include <hip/hip_runtime.h>
#include <hip/hip_bf16.h>
#include <cstdint>
#include <cstddef>
#include <type_traits>

constexpr int DIN = 64;
constexpr int DE  = 16;
constexpr int H   = 128;
constexpr int L   = 512;
constexpr int PD  = 1152;
constexpr int NAGG = 4096;  // agg stage-1 blocks (partials rows)

using bf16 = __hip_bfloat16;
typedef __attribute__((ext_vector_type(8))) short short8;
typedef __attribute__((ext_vector_type(4))) float float4v;

// ---- bf16 pack/unpack helpers (bf16x2 in a uint) ----
__device__ __forceinline__ float bflo(unsigned u) { return __uint_as_float(u << 16); }
__device__ __forceinline__ float bfhi(unsigned u) { return __uint_as_float(u & 0xffff0000u); }
__device__ __forceinline__ unsigned short f2b(float f) {
  bf16 h = __float2bfloat16(f);
  return *reinterpret_cast<unsigned short*>(&h);
}
__device__ __forceinline__ unsigned pack2(float a, float b) {
  return (unsigned)f2b(a) | ((unsigned)f2b(b) << 16);
}

// ---------------------------------------------------------------- zero fill
__global__ void k_zero_i32(int* p, int n) {
  int i = blockIdx.x * 256 + threadIdx.x;
  if (i < n) p[i] = 0;
}
__global__ void k_zero_f32(float* p, int n) {
  int i = blockIdx.x * 256 + threadIdx.x;
  if (i < n) p[i] = 0.f;
}

// fp32 -> bf16 (2 elements per thread)
__global__ void k_cvt_bf16(const float* __restrict__ in, bf16* __restrict__ out, int npairs) {
  int i = blockIdx.x * 256 + threadIdx.x;
  if (i >= npairs) return;
  float2 v = ((const float2*)in)[i];
  ((unsigned*)out)[i] = pack2(v.x, v.y);
}

// ---------------------------------------------------------------- CSR build
__global__ void k_deg(const int* __restrict__ dst, int* __restrict__ deg, int e) {
  int i = blockIdx.x * 256 + threadIdx.x;
  if (i < e) atomicAdd(&deg[dst[i]], 1);
}

__global__ void k_scan1(const int* __restrict__ deg, int* __restrict__ out,
                        int* __restrict__ bsum, int n) {
  __shared__ int tmp[512];
  int tid = threadIdx.x;
  int i = blockIdx.x * 512 + tid;
  int v = (i < n) ? deg[i] : 0;
  tmp[tid] = v; __syncthreads();
  for (int s = 1; s < 512; s <<= 1) {
    int t = (tid >= s) ? tmp[tid - s] : 0;
    __syncthreads();
    tmp[tid] += t;
    __syncthreads();
  }
  if (i < n) out[i] = tmp[tid] - v;
  if (tid == 511) bsum[blockIdx.x] = tmp[511];
}

__global__ void k_scan2(int* bsum, int nb) {  // nb <= 512
  __shared__ int tmp[512];
  int tid = threadIdx.x;
  int v = (tid < nb) ? bsum[tid] : 0;
  tmp[tid] = v; __syncthreads();
  for (int s = 1; s < 512; s <<= 1) {
    int t = (tid >= s) ? tmp[tid - s] : 0;
    __syncthreads();
    tmp[tid] += t;
    __syncthreads();
  }
  if (tid < nb) bsum[tid] = tmp[tid] - v;
}

__global__ void k_scan3(int* __restrict__ off, const int* __restrict__ bsum,
                        int* __restrict__ cursor, int n, int total) {
  int i = blockIdx.x * 512 + threadIdx.x;
  if (i < n) { int v = off[i] + bsum[blockIdx.x]; off[i] = v; cursor[i] = v; }
  if (i == 0) off[n] = total;
}

__global__ void k_fill(const int* __restrict__ dst, int* __restrict__ cursor,
                       int* __restrict__ eid, int e) {
  int i = blockIdx.x * 256 + threadIdx.x;
  if (i < e) { int slot = atomicAdd(&cursor[dst[i]], 1); eid[slot] = i; }
}

// ---------------------------------------------------------------- weall: all 14 conv edge-weight vectors [14][16]
__global__ void k_weall(const float* __restrict__ gWe, const float* __restrict__ ga_e,
                        const float* __restrict__ eWe1, const float* __restrict__ ea_e1,
                        const float* __restrict__ eWe2, const float* __restrict__ ea_e2,
                        float* __restrict__ weall) {
  int tid = threadIdx.x;
  if (tid >= 14 * 16) return;
  int c = tid >> 4, j = tid & 15;
  float acc = 0.f;
  if (c < 2) {
    for (int k = 0; k < 4; ++k) acc += gWe[(c * 16 + j) * 4 + k] * ga_e[c * 4 + k];
  } else if (c < 8) {
    int i = c - 2;
    for (int k = 0; k < 128; ++k) acc += eWe1[(i * 16 + j) * 128 + k] * ea_e1[i * 128 + k];
  } else {
    int i = c - 8;
    for (int k = 0; k < 128; ++k) acc += eWe2[(i * 16 + j) * 128 + k] * ea_e2[i * 128 + k];
  }
  weall[c * 16 + j] = acc;
}

// ---------------------------------------------------------------- weight repack into MFMA B-frag order (bf16)
__global__ void k_wpackall(const float* __restrict__ eW1, const float* __restrict__ eW2,
                           bf16* __restrict__ Wp1, bf16* __restrict__ Wp2) {
  int tid = blockIdx.x * 256 + threadIdx.x;
  const int L1TOT = 6 * 8192;
  if (tid < L1TOT) {
    int i = tid / 8192, r = tid % 8192;
    int kt = r / 4096, nt = (r / 512) & 7, l = (r / 8) & 63, j = r & 7;
    int k = kt * 32 + (l >> 4) * 8 + j, col = nt * 16 + (l & 15);
    Wp1[tid] = __float2bfloat16(eW1[(size_t)i * 64 * 128 + k * 128 + col]);
  } else {
    int t2 = tid - L1TOT;
    if (t2 >= 6 * 16384) return;
    int i = t2 / 16384, r = t2 % 16384;
    int kt = r / 4096, nt = (r / 512) & 7, l = (r / 8) & 63, j = r & 7;
    int k = kt * 32 + (l >> 4) * 8 + j, col = nt * 16 + (l & 15);
    Wp2[t2] = __float2bfloat16(eW2[(size_t)i * 128 * 128 + k * 128 + col]);
  }
}

// ---------------------------------------------------------------- CSR prep: src/dst in CSR order + all 14 edots
__global__ void k_csrprep(const int* __restrict__ eid, const int* __restrict__ src,
                          const int* __restrict__ dst, const float* __restrict__ eattr,
                          const float* __restrict__ weall, int* __restrict__ src_csr,
                          int* __restrict__ dst_csr, float* __restrict__ edots, int e) {
  __shared__ float w[14 * 16];
  if (threadIdx.x < 14 * 16) w[threadIdx.x] = weall[threadIdx.x];
  __syncthreads();
  int i = blockIdx.x * 256 + threadIdx.x;
  if (i >= e) return;
  int ed = eid[i];
  src_csr[i] = src[ed];
  dst_csr[i] = dst[ed];
  float ea[16];
  const float4* ep = (const float4*)(eattr + (size_t)ed * 16);
#pragma unroll
  for (int q = 0; q < 4; ++q) {
    float4 v = ep[q];
    ea[q * 4] = v.x; ea[q * 4 + 1] = v.y; ea[q * 4 + 2] = v.z; ea[q * 4 + 3] = v.w;
  }
#pragma unroll
  for (int c = 0; c < 14; ++c) {
    float acc = 0.f;
#pragma unroll
    for (int j = 0; j < 16; ++j) acc += ea[j] * w[c * 16 + j];
    edots[(size_t)c * e + i] = acc;
  }
}

// ---------------------------------------------------------------- MFMA GEMM: out[N,128](bf16) = A[N,K](bf16) @ W(packed)
// BN=true: apply BN1(scale/shift from partial-reduced stats) + leaky(0.01) to A during staging.
// Also fuses s[n] = out_row . a_s, d[n] = out_row . a_d
template <int K, bool BN>
__global__ __launch_bounds__(256) void k_mfma_gemm(
    const bf16* __restrict__ A, const bf16* __restrict__ Wp,
    const float* __restrict__ a_s, const float* __restrict__ a_d,
    bf16* __restrict__ out, float* __restrict__ s, float* __restrict__ d, int n,
    const float* __restrict__ bnsums, const float* __restrict__ bng,
    const float* __restrict__ bnb, float invn) {
  constexpr int KT = K / 32;
  __shared__ bf16 At[64][K + 8];
  __shared__ float sscale[128], sshift[128];
  if (BN) {
    if (threadIdx.x < K) {
      int c = threadIdx.x;
      float mu = bnsums[c] * invn;
      float var = bnsums[128 + c] * invn - mu * mu;
      float sc = rsqrtf(var + 1e-5f) * bng[c];
      sscale[c] = sc;
      sshift[c] = bnb[c] - mu * sc;
    }
    __syncthreads();
  }
  int row0 = blockIdx.x * 64;
  const int vecPerRow = K / 8;
  for (int idx = threadIdx.x; idx < 64 * vecPerRow; idx += 256) {
    int r = idx / vecPerRow, v = idx - r * vecPerRow;
    int gr = row0 + r;
    uint4 u = {0u, 0u, 0u, 0u};
    if (gr < n) u = ((const uint4*)(A + (size_t)gr * K))[v];
    if (BN) {
      float f[8] = {bflo(u.x), bfhi(u.x), bflo(u.y), bfhi(u.y),
                    bflo(u.z), bfhi(u.z), bflo(u.w), bfhi(u.w)};
      int c0 = v * 8;
#pragma unroll
      for (int j = 0; j < 8; ++j) {
        float y = f[j] * sscale[c0 + j] + sshift[c0 + j];
        f[j] = (y > 0.f) ? y : 0.01f * y;
      }
      u.x = pack2(f[0], f[1]); u.y = pack2(f[2], f[3]);
      u.z = pack2(f[4], f[5]); u.w = pack2(f[6], f[7]);
    }
    *((uint4*)&At[r][v * 8]) = u;
  }
  __syncthreads();
  int lane = threadIdx.x & 63, w = threadIdx.x >> 6;
  int c = lane & 15, q = lane >> 4;
  int wrow = w * 16;
  short8 afrag[KT];
#pragma unroll
  for (int kt = 0; kt < KT; ++kt)
    afrag[kt] = *(const short8*)&At[wrow + c][kt * 32 + q * 8];
  const short8* wp8 = (const short8*)Wp;
  float4v acc[8];
#pragma unroll
  for (int nt = 0; nt < 8; ++nt) acc[nt] = {0.f, 0.f, 0.f, 0.f};
#pragma unroll
  for (int kt = 0; kt < KT; ++kt) {
#pragma unroll
    for (int nt = 0; nt < 8; ++nt) {
      short8 bfrag = wp8[(kt * 8 + nt) * 64 + lane];
      acc[nt] = __builtin_amdgcn_mfma_f32_16x16x32_bf16(afrag[kt], bfrag, acc[nt], 0, 0, 0);
    }
  }
#pragma unroll
  for (int nt = 0; nt < 8; ++nt) {
#pragma unroll
    for (int reg = 0; reg < 4; ++reg) {
      int gr = row0 + wrow + q * 4 + reg;
      if (gr < n) out[(size_t)gr * 128 + nt * 16 + c] = __float2bfloat16(acc[nt][reg]);
    }
  }
#pragma unroll
  for (int reg = 0; reg < 4; ++reg) {
    float vs = 0.f, vd = 0.f;
#pragma unroll
    for (int nt = 0; nt < 8; ++nt) {
      float y = acc[nt][reg];
      int col = nt * 16 + c;
      vs += y * a_s[col];
      vd += y * a_d[col];
    }
#pragma unroll
    for (int o = 1; o < 16; o <<= 1) { vs += __shfl_xor(vs, o); vd += __shfl_xor(vd, o); }
    int gr = row0 + wrow + q * 4 + reg;
    if (c == 0 && gr < n) { s[gr] = vs; d[gr] = vd; }
  }
}

// ---------------------------------------------------------------- edge logits in CSR order
__global__ void k_edge_l(const int* __restrict__ src_csr, const int* __restrict__ dst_csr,
                         const float* __restrict__ edot, const float* __restrict__ s,
                         const float* __restrict__ d, float* __restrict__ lcsr, int e) {
  int i = blockIdx.x * 256 + threadIdx.x;
  if (i >= e) return;
  float l = s[src_csr[i]] + d[dst_csr[i]] + edot[i];
  lcsr[i] = (l > 0.f) ? l : 0.2f * l;
}

// ---------------------------------------------------------------- per-node softmax: lcsr (logits) -> alpha in place
__global__ void k_nodealpha(const int* __restrict__ off, float* __restrict__ lcsr, int n) {
  int node = blockIdx.x * 256 + threadIdx.x;
  if (node >= n) return;
  int e0 = off[node], e1 = off[node + 1];
  if (e0 == e1) return;
  float m = -INFINITY;
  for (int i = e0; i < e1; ++i) m = fmaxf(m, lcsr[i]);
  float den = 0.f;
  for (int i = e0; i < e1; ++i) {
    float ex = __expf(lcsr[i] - m);
    lcsr[i] = ex;
    den += ex;
  }
  float inv = 1.f / (den + 1e-16f);
  for (int i = e0; i < e1; ++i) lcsr[i] *= inv;
}

// ---------------------------------------------------------------- agg gather (alpha precomputed) + fused BN partials
// 8 nodes/block, 32 lanes/node; grid-stride; per-block partial sum/sumsq -> partials[block][256]
__global__ __launch_bounds__(256) void k_agg128v(
    const int* __restrict__ off, const int* __restrict__ src_csr,
    const float* __restrict__ alpha, const bf16* __restrict__ feat,
    const float* __restrict__ bias, bf16* __restrict__ out,
    float* __restrict__ partials, int n) {
  __shared__ float sm[8][128], sq2[8][128];
  int grp = threadIdx.x >> 5, lane = threadIdx.x & 31;
  float4 b4 = ((const float4*)bias)[lane];
  float s0 = 0.f, s1 = 0.f, s2 = 0.f, s3 = 0.f;
  float q0 = 0.f, q1 = 0.f, q2 = 0.f, q3 = 0.f;
  int stride = gridDim.x * 8;
  for (int node = blockIdx.x * 8 + grp; node < n; node += stride) {
    int e0 = off[node], e1 = off[node + 1];
    float a0 = 0.f, a1 = 0.f, a2 = 0.f, a3 = 0.f;
    for (int i = e0; i < e1; ++i) {
      float al = alpha[i];
      uint2 u = ((const uint2*)(feat + (size_t)src_csr[i] * 128))[lane];
      a0 += al * bflo(u.x);
      a1 += al * bfhi(u.x);
      a2 += al * bflo(u.y);
      a3 += al * bfhi(u.y);
    }
    a0 += b4.x; a1 += b4.y; a2 += b4.z; a3 += b4.w;
    uint2 o2;
    o2.x = pack2(a0, a1);
    o2.y = pack2(a2, a3);
    ((uint2*)(out + (size_t)node * 128))[lane] = o2;
    s0 += a0; s1 += a1; s2 += a2; s3 += a3;
    q0 += a0 * a0; q1 += a1 * a1; q2 += a2 * a2; q3 += a3 * a3;
  }
  sm[grp][lane * 4] = s0; sm[grp][lane * 4 + 1] = s1;
  sm[grp][lane * 4 + 2] = s2; sm[grp][lane * 4 + 3] = s3;
  sq2[grp][lane * 4] = q0; sq2[grp][lane * 4 + 1] = q1;
  sq2[grp][lane * 4 + 2] = q2; sq2[grp][lane * 4 + 3] = q3;
  __syncthreads();
  if (threadIdx.x < 128) {
    int c = threadIdx.x;
    float a = 0.f, b = 0.f;
#pragma unroll
    for (int g = 0; g < 8; ++g) { a += sm[g][c]; b += sq2[g][c]; }
    partials[(size_t)blockIdx.x * 256 + c] = a;
    partials[(size_t)blockIdx.x * 256 + 128 + c] = b;
  }
}

// ---------------------------------------------------------------- gate feature + s/d
__global__ void k_gfeat(const float* __restrict__ x, const float* __restrict__ W,
                        const float* __restrict__ a_s, const float* __restrict__ a_d,
                        float* __restrict__ gfeat, float* __restrict__ s,
                        float* __restrict__ d, int n) {
  int i = blockIdx.x * 256 + threadIdx.x;
  if (i >= n) return;
  const float* xr = x + (size_t)i * DIN;
  float acc[4] = {0.f, 0.f, 0.f, 0.f};
  for (int k = 0; k < DIN; ++k) {
    float xv = xr[k];
#pragma unroll
    for (int j = 0; j < 4; ++j) acc[j] += xv * W[k * 4 + j];
  }
  float ss = 0.f, dd = 0.f;
#pragma unroll
  for (int j = 0; j < 4; ++j) {
    gfeat[(size_t)i * 4 + j] = acc[j];
    ss += acc[j] * a_s[j];
    dd += acc[j] * a_d[j];
  }
  s[i] = ss; d[i] = dd;
}

// ---------------------------------------------------------------- gate aggregation + channel softmax
__global__ void k_agg4(const int* __restrict__ off, const int* __restrict__ src_csr,
                       const float* __restrict__ lcsr, const float* __restrict__ gfeat,
                       const float* __restrict__ bias, float* __restrict__ gates, int n) {
  int node = blockIdx.x * 256 + threadIdx.x;
  if (node >= n) return;
  int e0 = off[node], e1 = off[node + 1];
  float m = -INFINITY;
  for (int i = e0; i < e1; ++i) m = fmaxf(m, lcsr[i]);
  float den = 0.f;
  for (int i = e0; i < e1; ++i) den += __expf(lcsr[i] - m);
  float inv = 1.f / (den + 1e-16f);
  float4 acc = {0.f, 0.f, 0.f, 0.f};
  for (int i = e0; i < e1; ++i) {
    float a = __expf(lcsr[i] - m) * inv;
    float4 fr = *((const float4*)(gfeat + (size_t)src_csr[i] * 4));
    acc.x += a * fr.x; acc.y += a * fr.y; acc.z += a * fr.z; acc.w += a * fr.w;
  }
  float b0 = bias[0], b1 = bias[1], b2 = bias[2], b3 = bias[3];
  acc.x += b0; acc.y += b1; acc.z += b2; acc.w += b3;
  float mm = fmaxf(fmaxf(acc.x, acc.y), fmaxf(acc.z, acc.w));
  float e0s = __expf(acc.x - mm), e1s = __expf(acc.y - mm);
  float e2s = __expf(acc.z - mm), e3s = __expf(acc.w - mm);
  float is = 1.f / (e0s + e1s + e2s + e3s);
  float4 g4 = {e0s * is, e1s * is, e2s * is, e3s * is};
  *((float4*)(gates + (size_t)node * 4)) = g4;
}

// stage 2: reduce partials -> sums[0..127], sums[128..255]. grid = 16 blocks x 8 ch.
__global__ void k_bnstats_fin(const float* __restrict__ partials, float* __restrict__ sums,
                              int nblk) {
  int t = threadIdx.x;
  int cl = t >> 5, sl = t & 31;
  int ch = blockIdx.x * 8 + cl;
  float a = 0.f, b = 0.f;
  for (int blk = sl; blk < nblk; blk += 32) {
    a += partials[(size_t)blk * 256 + ch];
    b += partials[(size_t)blk * 256 + 128 + ch];
  }
#pragma unroll
  for (int o = 16; o; o >>= 1) { a += __shfl_xor(a, o); b += __shfl_xor(b, o); }
  if (sl == 0) { sums[ch] = a; sums[128 + ch] = b; }
}

// BN stats fp32 (head path, tiny)
__global__ void k_bnstats_f32(const float* __restrict__ x, float* __restrict__ sums,
                              float* __restrict__ sumsq, int n) {
  __shared__ float s1[256], s2[256];
  int c = threadIdx.x & 127, half = threadIdx.x >> 7;
  float a = 0.f, b = 0.f;
  for (int r = blockIdx.x * 2 + half; r < n; r += gridDim.x * 2) {
    float v = x[(size_t)r * 128 + c];
    a += v; b += v * v;
  }
  s1[threadIdx.x] = a; s2[threadIdx.x] = b;
  __syncthreads();
  if (half == 0) {
    atomicAdd(&sums[c], s1[c] + s1[c + 128]);
    atomicAdd(&sumsq[c], s2[c] + s2[c + 128]);
  }
}

// ---------------------------------------------------------------- fused BN2+leaky+gate+pool
__global__ void k_poolexpert(const bf16* __restrict__ x, const float* __restrict__ sums,
                             const float* __restrict__ sumsq, const float* __restrict__ g,
                             const float* __restrict__ bb, const int* __restrict__ batch,
                             const float* __restrict__ gates0, int slot0,
                             const float* __restrict__ gates1, int slot1,
                             float* __restrict__ pooled0, float* __restrict__ pooled1,
                             int n, float invn) {
  int b = blockIdx.x, t = threadIdx.x;
  int lo = 0, hi = n;
  while (lo < hi) { int m = (lo + hi) >> 1; if (batch[m] < b) lo = m + 1; else hi = m; }
  int start = lo;
  lo = start; hi = n;
  while (lo < hi) { int m = (lo + hi) >> 1; if (batch[m] < b + 1) lo = m + 1; else hi = m; }
  int end = lo;
  int c0 = 2 * t, c1 = 2 * t + 1;
  float mu0 = sums[c0] * invn, mu1 = sums[c1] * invn;
  float sc0 = rsqrtf(sumsq[c0] * invn - mu0 * mu0 + 1e-5f) * g[c0];
  float sc1 = rsqrtf(sumsq[c1] * invn - mu1 * mu1 + 1e-5f) * g[c1];
  float sh0 = bb[c0], sh1 = bb[c1];
  float a00 = 0.f, a01 = 0.f, a10 = 0.f, a11 = 0.f;
  for (int r = start; r < end; ++r) {
    unsigned u = ((const unsigned*)(x + (size_t)r * 128))[t];
    float y0 = (bflo(u) - mu0) * sc0 + sh0;
    float y1 = (bfhi(u) - mu1) * sc1 + sh1;
    y0 = (y0 > 0.f) ? y0 : 0.01f * y0;
    y1 = (y1 > 0.f) ? y1 : 0.01f * y1;
    if (slot0 >= 0) {
      float gw = gates0[(size_t)r * 4 + slot0];
      a00 += gw * y0; a01 += gw * y1;
    }
    if (slot1 >= 0) {
      float gw = gates1[(size_t)r * 4 + slot1];
      a10 += gw * y0; a11 += gw * y1;
    }
  }
  if (slot0 >= 0) {
    pooled0[(size_t)b * 128 + c0] += a00;
    pooled0[(size_t)b * 128 + c1] += a01;
  }
  if (slot1 >= 0) {
    pooled1[(size_t)b * 128 + c0] += a10;
    pooled1[(size_t)b * 128 + c1] += a11;
  }
}

// ---------------------------------------------------------------- K^T = (pe@Wk)^T [128][L], V = pe@Wv [L][128]
__global__ void k_kv(const float* __restrict__ pe, const float* __restrict__ Wk,
                     const float* __restrict__ Wv, float* __restrict__ Kt,
                     float* __restrict__ Vout) {
  __shared__ float per[PD];
  int l = blockIdx.x, c = threadIdx.x;
  for (int p = threadIdx.x; p < PD; p += 128) per[p] = pe[(size_t)l * PD + p];
  __syncthreads();
  float ak = 0.f, av = 0.f;
  for (int p = 0; p < PD; ++p) {
    float v = per[p];
    ak += v * Wk[p * 128 + c];
    av += v * Wv[p * 128 + c];
  }
  Kt[(size_t)c * L + l] = ak;
  Vout[(size_t)l * 128 + c] = av;
}

// out[row,:] = in[row,:Kdim] @ W[Kdim,128]
__global__ void k_rowgemm(const float* __restrict__ in, const float* __restrict__ W,
                          float* __restrict__ out, int Kdim) {
  __shared__ float rr[256];
  int row = blockIdx.x, c = threadIdx.x;
  for (int k = threadIdx.x; k < Kdim; k += 128) rr[k] = in[(size_t)row * Kdim + k];
  __syncthreads();
  float acc = 0.f;
  for (int k = 0; k < Kdim; ++k) acc += rr[k] * W[k * 128 + c];
  out[(size_t)row * 128 + c] = acc;
}

// ---------------------------------------------------------------- cross-attention, 4 graphs per block
__global__ void k_attn(const float* __restrict__ Q, const float* __restrict__ Kt,
                       const float* __restrict__ Vm, float* __restrict__ ctx) {
  __shared__ float q[4][128];
  __shared__ float sc[4][L];
  __shared__ float4 red[128];
  __shared__ float4 Mg, Ig;
  int b0 = blockIdx.x * 4, t = threadIdx.x;
#pragma unroll
  for (int g = 0; g < 4; ++g) q[g][t] = Q[(size_t)(b0 + g) * 128 + t];
  __syncthreads();
  float acc[4][4];
#pragma unroll
  for (int g = 0; g < 4; ++g)
#pragma unroll
    for (int j = 0; j < 4; ++j) acc[g][j] = 0.f;
  for (int k = 0; k < 128; ++k) {
    const float* kr = Kt + (size_t)k * L + t;
    float k0 = kr[0], k1 = kr[128], k2 = kr[256], k3 = kr[384];
#pragma unroll
    for (int g = 0; g < 4; ++g) {
      float qv = q[g][k];
      acc[g][0] += qv * k0; acc[g][1] += qv * k1;
      acc[g][2] += qv * k2; acc[g][3] += qv * k3;
    }
  }
  const float scale = 0.08838834764831845f;
  float4 pm;
  {
    float m[4];
#pragma unroll
    for (int g = 0; g < 4; ++g) {
#pragma unroll
      for (int j = 0; j < 4; ++j) {
        acc[g][j] *= scale;
        sc[g][t + j * 128] = acc[g][j];
      }
      m[g] = fmaxf(fmaxf(acc[g][0], acc[g][1]), fmaxf(acc[g][2], acc[g][3]));
    }
    pm = {m[0], m[1], m[2], m[3]};
  }
  red[t] = pm; __syncthreads();
  for (int s = 64; s > 0; s >>= 1) {
    if (t < s) {
      float4 o = red[t + s];
      red[t].x = fmaxf(red[t].x, o.x); red[t].y = fmaxf(red[t].y, o.y);
      red[t].z = fmaxf(red[t].z, o.z); red[t].w = fmaxf(red[t].w, o.w);
    }
    __syncthreads();
  }
  if (t == 0) Mg = red[0];
  __syncthreads();
  float4 M = Mg;
  float4 ps = {0, 0, 0, 0};
#pragma unroll
  for (int g = 0; g < 4; ++g) {
    float mg = (g == 0) ? M.x : (g == 1) ? M.y : (g == 2) ? M.z : M.w;
    float sgsum = 0.f;
#pragma unroll
    for (int j = 0; j < 4; ++j) {
      float e = __expf(acc[g][j] - mg);
      sc[g][t + j * 128] = e;
      sgsum += e;
    }
    if (g == 0) ps.x = sgsum; else if (g == 1) ps.y = sgsum;
    else if (g == 2) ps.z = sgsum; else ps.w = sgsum;
  }
  __syncthreads();
  red[t] = ps; __syncthreads();
  for (int s = 64; s > 0; s >>= 1) {
    if (t < s) {
      float4 o = red[t + s];
      red[t].x += o.x; red[t].y += o.y; red[t].z += o.z; red[t].w += o.w;
    }
    __syncthreads();
  }
  if (t == 0) Ig = {1.f / red[0].x, 1.f / red[0].y, 1.f / red[0].z, 1.f / red[0].w};
  __syncthreads();
  float4 I = Ig;
  float o0 = 0.f, o1 = 0.f, o2 = 0.f, o3 = 0.f;
  for (int l = 0; l < L; ++l) {
    float v = Vm[(size_t)l * 128 + t];
    o0 += sc[0][l] * v; o1 += sc[1][l] * v; o2 += sc[2][l] * v; o3 += sc[3][l] * v;
  }
  ctx[(size_t)(b0 + 0) * 128 + t] = o0 * I.x;
  ctx[(size_t)(b0 + 1) * 128 + t] = o1 * I.y;
  ctx[(size_t)(b0 + 2) * 128 + t] = o2 * I.z;
  ctx[(size_t)(b0 + 3) * 128 + t] = o3 * I.w;
}

// hh = concat(pooled, ctx) @ Wh1 + bh1
__global__ void k_head1(const float* __restrict__ pooled, const float* __restrict__ ctx,
                        const float* __restrict__ Wh1, const float* __restrict__ bh1,
                        float* __restrict__ hh) {
  __shared__ float f[256];
  int b = blockIdx.x, c = threadIdx.x;
  f[c] = pooled[(size_t)b * 128 + c];
  f[c + 128] = ctx[(size_t)b * 128 + c];
  __syncthreads();
  float acc = bh1[c];
  for (int k = 0; k < 256; ++k) acc += f[k] * Wh1[k * 128 + c];
  hh[(size_t)b * 128 + c] = acc;
}

// bn + leaky + final dot with Wh2 -> out[b*2+t]
__global__ void k_head2(const float* __restrict__ hh, const float* __restrict__ sums,
                        const float* __restrict__ sumsq, const float* __restrict__ g,
                        const float* __restrict__ bbn, const float* __restrict__ Wh2,
                        const float* __restrict__ bh2, float* __restrict__ out, int t,
                        float invn) {
  __shared__ float red[2];
  int b = blockIdx.x, c = threadIdx.x;
  float mu = sums[c] * invn;
  float var = sumsq[c] * invn - mu * mu;
  float y = (hh[(size_t)b * 128 + c] - mu) * rsqrtf(var + 1e-5f) * g[c] + bbn[c];
  y = (y > 0.f) ? y : 0.01f * y;
  float p = y * Wh2[c];
  for (int o = 32; o; o >>= 1) p += __shfl_down(p, o);
  if ((threadIdx.x & 63) == 0) red[threadIdx.x >> 6] = p;
  __syncthreads();
  if (threadIdx.x == 0) out[(size_t)b * 2 + t] = red[0] + red[1] + bh2[0];
}

extern "C" void kernel_launch(void* const* d_in, const int* in_sizes, int n_in,
                              void* d_out, int out_size, void* d_ws, size_t ws_size,
                              hipStream_t stream) {
  (void)n_in; (void)ws_size;
  const float* x     = (const float*)d_in[0];
  const int*   eidx  = (const int*)d_in[1];
  const float* eattr = (const float*)d_in[2];
  const int*   batch = (const int*)d_in[3];
  const float* eW1   = (const float*)d_in[4];
  const float* ea_s1 = (const float*)d_in[5];
  const float* ea_d1 = (const float*)d_in[6];
  const float* eWe1  = (const float*)d_in[7];
  const float* ea_e1 = (const float*)d_in[8];
  const float* eb1   = (const float*)d_in[9];
  const float* bn1_g = (const float*)d_in[10];
  const float* bn1_b = (const float*)d_in[11];
  const float* eW2   = (const float*)d_in[12];
  const float* ea_s2 = (const float*)d_in[13];
  const float* ea_d2 = (const float*)d_in[14];
  const float* eWe2  = (const float*)d_in[15];
  const float* ea_e2 = (const float*)d_in[16];
  const float* eb2   = (const float*)d_in[17];
  const float* bn2_g = (const float*)d_in[18];
  const float* bn2_b = (const float*)d_in[19];
  const float* gW    = (const float*)d_in[20];
  const float* ga_s  = (const float*)d_in[21];
  const float* ga_d  = (const float*)d_in[22];
  const float* gWe   = (const float*)d_in[23];
  const float* ga_e  = (const float*)d_in[24];
  const float* gb    = (const float*)d_in[25];
  const float* Wq    = (const float*)d_in[26];
  const float* Wk    = (const float*)d_in[27];
  const float* Wv    = (const float*)d_in[28];
  const float* pe    = (const float*)d_in[29];
  const float* Wh1   = (const float*)d_in[30];
  const float* bh1   = (const float*)d_in[31];
  const float* hbn_g = (const float*)d_in[32];
  const float* hbn_b = (const float*)d_in[33];
  const float* Wh2   = (const float*)d_in[34];
  const float* bh2   = (const float*)d_in[35];
  float* out = (float*)d_out;

  const int n = in_sizes[0] / DIN;    // 200000
  const int e = in_sizes[1] / 2;      // 800000
  const int nb_graphs = out_size / 2; // 4096
  const int* src = eidx;
  const int* dst = eidx + e;

  char* p = (char*)d_ws;
  auto carve = [&](size_t bytes) {
    void* r = (void*)p;
    p += (bytes + 255) & ~(size_t)255;
    return r;
  };
  int* deg       = (int*)carve((size_t)n * 4);
  int* off       = (int*)carve(((size_t)n + 1) * 4);
  int* cursor    = (int*)carve((size_t)n * 4);
  int* eid       = (int*)carve((size_t)e * 4);
  int* bsum      = (int*)carve(4096);
  int* src_csr   = (int*)carve((size_t)e * 4);
  int* dst_csr   = (int*)carve((size_t)e * 4);
  float* edots   = (float*)carve((size_t)14 * e * 4);
  float* weall   = (float*)carve(14 * 16 * 4);
  float* s_arr   = (float*)carve((size_t)n * 4);
  float* d_arr   = (float*)carve((size_t)n * 4);
  float* lcsr    = (float*)carve((size_t)e * 4);
  float* sums    = (float*)carve(256 * 4);
  float* partials = (float*)carve((size_t)NAGG * 256 * 4);
  float* gates0  = (float*)carve((size_t)n * 16);
  float* gates1  = (float*)carve((size_t)n * 16);
  float* gfeat   = (float*)carve((size_t)n * 16);
  float* pooled0 = (float*)carve((size_t)nb_graphs * H * 4);
  float* pooled1 = (float*)carve((size_t)nb_graphs * H * 4);
  float* Ktbuf   = (float*)carve((size_t)L * H * 4);
  float* Vbuf    = (float*)carve((size_t)L * H * 4);
  float* Qbuf    = (float*)carve((size_t)nb_graphs * H * 4);
  float* ctxb    = (float*)carve((size_t)nb_graphs * H * 4);
  float* hhb     = (float*)carve((size_t)nb_graphs * H * 4);
  bf16* featbuf  = (bf16*)carve((size_t)n * H * 2);
  bf16* buf1     = (bf16*)carve((size_t)n * H * 2);
  bf16* xbf      = (bf16*)carve((size_t)n * DIN * 2);
  bf16* Wp1      = (bf16*)carve((size_t)6 * 8192 * 2);
  bf16* Wp2      = (bf16*)carve((size_t)6 * 16384 * 2);

  float invn = 1.0f / n;

  // ---- one-time prep: x->bf16, weight repack
  k_cvt_bf16<<<(n * DIN / 2 + 255) / 256, 256, 0, stream>>>(x, xbf, n * DIN / 2);
  k_wpackall<<<(6 * 8192 + 6 * 16384 + 255) / 256, 256, 0, stream>>>(eW1, eW2, Wp1, Wp2);

  // ---- CSR by dst (reused by all 14 GAT convs)
  k_zero_i32<<<(n + 255) / 256, 256, 0, stream>>>(deg, n);
  k_deg<<<(e + 255) / 256, 256, 0, stream>>>(dst, deg, e);
  int nsb = (n + 511) / 512;
  k_scan1<<<nsb, 512, 0, stream>>>(deg, off, bsum, n);
  k_scan2<<<1, 512, 0, stream>>>(bsum, nsb);
  k_scan3<<<nsb, 512, 0, stream>>>(off, bsum, cursor, n, e);
  k_fill<<<(e + 255) / 256, 256, 0, stream>>>(dst, cursor, eid, e);

  // ---- all 14 edge-weight dots in CSR order
  k_weall<<<1, 256, 0, stream>>>(gWe, ga_e, eWe1, ea_e1, eWe2, ea_e2, weall);
  k_csrprep<<<(e + 255) / 256, 256, 0, stream>>>(eid, src, dst, eattr, weall, src_csr,
                                                 dst_csr, edots, e);

  // ---- gates (2 tasks)
  for (int t = 0; t < 2; ++t) {
    float* gates = t ? gates1 : gates0;
    k_gfeat<<<(n + 255) / 256, 256, 0, stream>>>(x, gW + t * DIN * 4, ga_s + t * 4,
                                                 ga_d + t * 4, gfeat, s_arr, d_arr, n);
    k_edge_l<<<(e + 255) / 256, 256, 0, stream>>>(src_csr, dst_csr, edots + (size_t)t * e,
                                                  s_arr, d_arr, lcsr, e);
    k_agg4<<<(n + 255) / 256, 256, 0, stream>>>(off, src_csr, lcsr, gfeat, gb + t * 4,
                                                gates, n);
  }

  // ---- zero pooled accumulators
  k_zero_f32<<<(nb_graphs * H + 255) / 256, 256, 0, stream>>>(pooled0, nb_graphs * H);
  k_zero_f32<<<(nb_graphs * H + 255) / 256, 256, 0, stream>>>(pooled1, nb_graphs * H);

  // ---- 6 experts (MFMA GEMMs; BN1 fused into layer-2 staging; alpha precomputed; agg fuses BN partials)
  int gblk = (n + 63) / 64;
  for (int i = 0; i < 6; ++i) {
    // layer 1 (DIN -> H)
    k_mfma_gemm<DIN, false><<<gblk, 256, 0, stream>>>(
        xbf, Wp1 + (size_t)i * 8192, ea_s1 + i * H, ea_d1 + i * H, featbuf, s_arr, d_arr,
        n, nullptr, nullptr, nullptr, 0.f);
    k_edge_l<<<(e + 255) / 256, 256, 0, stream>>>(src_csr, dst_csr,
                                                  edots + (size_t)(2 + i) * e, s_arr,
                                                  d_arr, lcsr, e);
    k_nodealpha<<<(n + 255) / 256, 256, 0, stream>>>(off, lcsr, n);
    k_agg128v<<<NAGG, 256, 0, stream>>>(off, src_csr, lcsr, featbuf, eb1 + i * H, buf1,
                                        partials, n);
    k_bnstats_fin<<<16, 256, 0, stream>>>(partials, sums, NAGG);
    // layer 2 (H -> H); BN1 + leaky applied during A staging
    k_mfma_gemm<H, true><<<gblk, 256, 0, stream>>>(
        buf1, Wp2 + (size_t)i * 16384, ea_s2 + i * H, ea_d2 + i * H, featbuf, s_arr,
        d_arr, n, sums, bn1_g + i * H, bn1_b + i * H, invn);
    k_edge_l<<<(e + 255) / 256, 256, 0, stream>>>(src_csr, dst_csr,
                                                  edots + (size_t)(8 + i) * e, s_arr,
                                                  d_arr, lcsr, e);
    k_nodealpha<<<(n + 255) / 256, 256, 0, stream>>>(off, lcsr, n);
    k_agg128v<<<NAGG, 256, 0, stream>>>(off, src_csr, lcsr, featbuf, eb2 + i * H, buf1,
                                        partials, n);
    k_bnstats_fin<<<16, 256, 0, stream>>>(partials, sums, NAGG);
    int s0 = (i < 4) ? i : -1;
    int s1 = (i < 2) ? i : (i >= 4 ? i - 2 : -1);
    k_poolexpert<<<nb_graphs, 64, 0, stream>>>(buf1, sums, sums + 128, bn2_g + i * H,
                                               bn2_b + i * H, batch, gates0, s0, gates1,
                                               s1, pooled0, pooled1, n, invn);
  }

  // ---- heads
  for (int t = 0; t < 2; ++t) {
    const float* pooled = t ? pooled1 : pooled0;
    k_kv<<<L, 128, 0, stream>>>(pe + (size_t)t * L * PD, Wk + t * PD * H, Wv + t * PD * H,
                                Ktbuf, Vbuf);
    k_rowgemm<<<nb_graphs, 128, 0, stream>>>(pooled, Wq + t * H * H, Qbuf, H);
    k_attn<<<nb_graphs / 4, 128, 0, stream>>>(Qbuf, Ktbuf, Vbuf, ctxb);
    k_head1<<<nb_graphs, 128, 0, stream>>>(pooled, ctxb, Wh1 + t * 2 * H * H, bh1 + t * H,
                                           hhb);
    k_zero_f32<<<1, 256, 0, stream>>>(sums, 256);
    k_bnstats_f32<<<64, 256, 0, stream>>>(hhb, sums, sums + 128, nb_graphs);
    k_head2<<<nb_graphs, 128, 0, stream>>>(hhb, sums, sums + 128, hbn_g + t * H,
                                           hbn_b + t * H, Wh2 + t * H, bh2 + t, out, t,
                                           1.0f / nb_graphs);
  }
}

// Round 8
// 2648.622 us; speedup vs baseline: 1.2079x; 1.0929x over previous
//
#include <hip/hip_runtime.h>
#include <hip/hip_bf16.h>
#include <cstdint>
#include <cstddef>
#include <type_traits>

constexpr int DIN = 64;
constexpr int DE  = 16;
constexpr int H   = 128;
constexpr int L   = 512;
constexpr int PD  = 1152;
constexpr int NAGG = 4096;  // agg stage-1 blocks (partials rows)

using bf16 = __hip_bfloat16;
typedef __attribute__((ext_vector_type(8))) short short8;
typedef __attribute__((ext_vector_type(4))) float float4v;

// ---- bf16 pack/unpack helpers (bf16x2 in a uint) ----
__device__ __forceinline__ float bflo(unsigned u) { return __uint_as_float(u << 16); }
__device__ __forceinline__ float bfhi(unsigned u) { return __uint_as_float(u & 0xffff0000u); }
__device__ __forceinline__ unsigned short f2b(float f) {
  bf16 h = __float2bfloat16(f);
  return *reinterpret_cast<unsigned short*>(&h);
}
__device__ __forceinline__ unsigned pack2(float a, float b) {
  return (unsigned)f2b(a) | ((unsigned)f2b(b) << 16);
}

// ---------------------------------------------------------------- zero fill
__global__ void k_zero_i32(int* p, int n) {
  int i = blockIdx.x * 256 + threadIdx.x;
  if (i < n) p[i] = 0;
}
__global__ void k_zero_f32(float* p, int n) {
  int i = blockIdx.x * 256 + threadIdx.x;
  if (i < n) p[i] = 0.f;
}

// fp32 -> bf16 (2 elements per thread)
__global__ void k_cvt_bf16(const float* __restrict__ in, bf16* __restrict__ out, int npairs) {
  int i = blockIdx.x * 256 + threadIdx.x;
  if (i >= npairs) return;
  float2 v = ((const float2*)in)[i];
  ((unsigned*)out)[i] = pack2(v.x, v.y);
}

// ---------------------------------------------------------------- CSR build
__global__ void k_deg(const int* __restrict__ dst, int* __restrict__ deg, int e) {
  int i = blockIdx.x * 256 + threadIdx.x;
  if (i < e) atomicAdd(&deg[dst[i]], 1);
}

__global__ void k_scan1(const int* __restrict__ deg, int* __restrict__ out,
                        int* __restrict__ bsum, int n) {
  __shared__ int tmp[512];
  int tid = threadIdx.x;
  int i = blockIdx.x * 512 + tid;
  int v = (i < n) ? deg[i] : 0;
  tmp[tid] = v; __syncthreads();
  for (int s = 1; s < 512; s <<= 1) {
    int t = (tid >= s) ? tmp[tid - s] : 0;
    __syncthreads();
    tmp[tid] += t;
    __syncthreads();
  }
  if (i < n) out[i] = tmp[tid] - v;
  if (tid == 511) bsum[blockIdx.x] = tmp[511];
}

__global__ void k_scan2(int* bsum, int nb) {  // nb <= 512
  __shared__ int tmp[512];
  int tid = threadIdx.x;
  int v = (tid < nb) ? bsum[tid] : 0;
  tmp[tid] = v; __syncthreads();
  for (int s = 1; s < 512; s <<= 1) {
    int t = (tid >= s) ? tmp[tid - s] : 0;
    __syncthreads();
    tmp[tid] += t;
    __syncthreads();
  }
  if (tid < nb) bsum[tid] = tmp[tid] - v;
}

__global__ void k_scan3(int* __restrict__ off, const int* __restrict__ bsum,
                        int* __restrict__ cursor, int n, int total) {
  int i = blockIdx.x * 512 + threadIdx.x;
  if (i < n) { int v = off[i] + bsum[blockIdx.x]; off[i] = v; cursor[i] = v; }
  if (i == 0) off[n] = total;
}

__global__ void k_fill(const int* __restrict__ dst, int* __restrict__ cursor,
                       int* __restrict__ eid, int e) {
  int i = blockIdx.x * 256 + threadIdx.x;
  if (i < e) { int slot = atomicAdd(&cursor[dst[i]], 1); eid[slot] = i; }
}

// ---------------------------------------------------------------- weall: all 14 conv edge-weight vectors [14][16]
__global__ void k_weall(const float* __restrict__ gWe, const float* __restrict__ ga_e,
                        const float* __restrict__ eWe1, const float* __restrict__ ea_e1,
                        const float* __restrict__ eWe2, const float* __restrict__ ea_e2,
                        float* __restrict__ weall) {
  int tid = threadIdx.x;
  if (tid >= 14 * 16) return;
  int c = tid >> 4, j = tid & 15;
  float acc = 0.f;
  if (c < 2) {
    for (int k = 0; k < 4; ++k) acc += gWe[(c * 16 + j) * 4 + k] * ga_e[c * 4 + k];
  } else if (c < 8) {
    int i = c - 2;
    for (int k = 0; k < 128; ++k) acc += eWe1[(i * 16 + j) * 128 + k] * ea_e1[i * 128 + k];
  } else {
    int i = c - 8;
    for (int k = 0; k < 128; ++k) acc += eWe2[(i * 16 + j) * 128 + k] * ea_e2[i * 128 + k];
  }
  weall[c * 16 + j] = acc;
}

// ---------------------------------------------------------------- weight repack into MFMA B-frag order (bf16)
__global__ void k_wpackall(const float* __restrict__ eW1, const float* __restrict__ eW2,
                           bf16* __restrict__ Wp1, bf16* __restrict__ Wp2) {
  int tid = blockIdx.x * 256 + threadIdx.x;
  const int L1TOT = 6 * 8192;
  if (tid < L1TOT) {
    int i = tid / 8192, r = tid % 8192;
    int kt = r / 4096, nt = (r / 512) & 7, l = (r / 8) & 63, j = r & 7;
    int k = kt * 32 + (l >> 4) * 8 + j, col = nt * 16 + (l & 15);
    Wp1[tid] = __float2bfloat16(eW1[(size_t)i * 64 * 128 + k * 128 + col]);
  } else {
    int t2 = tid - L1TOT;
    if (t2 >= 6 * 16384) return;
    int i = t2 / 16384, r = t2 % 16384;
    int kt = r / 4096, nt = (r / 512) & 7, l = (r / 8) & 63, j = r & 7;
    int k = kt * 32 + (l >> 4) * 8 + j, col = nt * 16 + (l & 15);
    Wp2[t2] = __float2bfloat16(eW2[(size_t)i * 128 * 128 + k * 128 + col]);
  }
}

// ---------------------------------------------------------------- CSR prep: src/dst in CSR order + all 14 edots
__global__ void k_csrprep(const int* __restrict__ eid, const int* __restrict__ src,
                          const int* __restrict__ dst, const float* __restrict__ eattr,
                          const float* __restrict__ weall, int* __restrict__ src_csr,
                          int* __restrict__ dst_csr, float* __restrict__ edots, int e) {
  __shared__ float w[14 * 16];
  if (threadIdx.x < 14 * 16) w[threadIdx.x] = weall[threadIdx.x];
  __syncthreads();
  int i = blockIdx.x * 256 + threadIdx.x;
  if (i >= e) return;
  int ed = eid[i];
  src_csr[i] = src[ed];
  dst_csr[i] = dst[ed];
  float ea[16];
  const float4* ep = (const float4*)(eattr + (size_t)ed * 16);
#pragma unroll
  for (int q = 0; q < 4; ++q) {
    float4 v = ep[q];
    ea[q * 4] = v.x; ea[q * 4 + 1] = v.y; ea[q * 4 + 2] = v.z; ea[q * 4 + 3] = v.w;
  }
#pragma unroll
  for (int c = 0; c < 14; ++c) {
    float acc = 0.f;
#pragma unroll
    for (int j = 0; j < 16; ++j) acc += ea[j] * w[c * 16 + j];
    edots[(size_t)c * e + i] = acc;
  }
}

// ---------------------------------------------------------------- MFMA GEMM: out[N,128](bf16) = A[N,K](bf16) @ W(packed)
// BN=true: apply BN1(scale/shift) + leaky(0.01) to A during staging.
// Fuses s[n] = out_row . a_s, d[n] = out_row . a_d. Output staged via LDS for
// coalesced uint4 stores (was: 32 scalar 2B stores/thread).
template <int K, bool BN>
__global__ __launch_bounds__(256) void k_mfma_gemm(
    const bf16* __restrict__ A, const bf16* __restrict__ Wp,
    const float* __restrict__ a_s, const float* __restrict__ a_d,
    bf16* __restrict__ out, float* __restrict__ s, float* __restrict__ d, int n,
    const float* __restrict__ bnsums, const float* __restrict__ bng,
    const float* __restrict__ bnb, float invn) {
  constexpr int KT = K / 32;
  __shared__ bf16 At[64][K + 8];
  __shared__ bf16 Ct[64][128 + 8];
  __shared__ float sscale[128], sshift[128];
  if (BN) {
    if (threadIdx.x < K) {
      int c = threadIdx.x;
      float mu = bnsums[c] * invn;
      float var = bnsums[128 + c] * invn - mu * mu;
      float sc = rsqrtf(var + 1e-5f) * bng[c];
      sscale[c] = sc;
      sshift[c] = bnb[c] - mu * sc;
    }
    __syncthreads();
  }
  int row0 = blockIdx.x * 64;
  const int vecPerRow = K / 8;
  for (int idx = threadIdx.x; idx < 64 * vecPerRow; idx += 256) {
    int r = idx / vecPerRow, v = idx - r * vecPerRow;
    int gr = row0 + r;
    uint4 u = {0u, 0u, 0u, 0u};
    if (gr < n) u = ((const uint4*)(A + (size_t)gr * K))[v];
    if (BN) {
      float f[8] = {bflo(u.x), bfhi(u.x), bflo(u.y), bfhi(u.y),
                    bflo(u.z), bfhi(u.z), bflo(u.w), bfhi(u.w)};
      int c0 = v * 8;
#pragma unroll
      for (int j = 0; j < 8; ++j) {
        float y = f[j] * sscale[c0 + j] + sshift[c0 + j];
        f[j] = (y > 0.f) ? y : 0.01f * y;
      }
      u.x = pack2(f[0], f[1]); u.y = pack2(f[2], f[3]);
      u.z = pack2(f[4], f[5]); u.w = pack2(f[6], f[7]);
    }
    *((uint4*)&At[r][v * 8]) = u;
  }
  __syncthreads();
  int lane = threadIdx.x & 63, w = threadIdx.x >> 6;
  int c = lane & 15, q = lane >> 4;
  int wrow = w * 16;
  short8 afrag[KT];
#pragma unroll
  for (int kt = 0; kt < KT; ++kt)
    afrag[kt] = *(const short8*)&At[wrow + c][kt * 32 + q * 8];
  const short8* wp8 = (const short8*)Wp;
  float4v acc[8];
#pragma unroll
  for (int nt = 0; nt < 8; ++nt) acc[nt] = {0.f, 0.f, 0.f, 0.f};
#pragma unroll
  for (int kt = 0; kt < KT; ++kt) {
#pragma unroll
    for (int nt = 0; nt < 8; ++nt) {
      short8 bfrag = wp8[(kt * 8 + nt) * 64 + lane];
      acc[nt] = __builtin_amdgcn_mfma_f32_16x16x32_bf16(afrag[kt], bfrag, acc[nt], 0, 0, 0);
    }
  }
  // fused s/d epilogue (from fp32 accumulators)
#pragma unroll
  for (int reg = 0; reg < 4; ++reg) {
    float vs = 0.f, vd = 0.f;
#pragma unroll
    for (int nt = 0; nt < 8; ++nt) {
      float y = acc[nt][reg];
      int col = nt * 16 + c;
      vs += y * a_s[col];
      vd += y * a_d[col];
    }
#pragma unroll
    for (int o = 1; o < 16; o <<= 1) { vs += __shfl_xor(vs, o); vd += __shfl_xor(vd, o); }
    int gr = row0 + wrow + q * 4 + reg;
    if (c == 0 && gr < n) { s[gr] = vs; d[gr] = vd; }
  }
  // stage C into LDS, then coalesced uint4 stores
#pragma unroll
  for (int nt = 0; nt < 8; ++nt)
#pragma unroll
    for (int reg = 0; reg < 4; ++reg)
      Ct[wrow + q * 4 + reg][nt * 16 + c] = __float2bfloat16(acc[nt][reg]);
  __syncthreads();
#pragma unroll
  for (int k2 = 0; k2 < 4; ++k2) {
    int idx = threadIdx.x + k2 * 256;  // 0..1023
    int r = idx >> 4, v = idx & 15;
    int gr = row0 + r;
    if (gr < n) ((uint4*)(out + (size_t)gr * 128))[v] = *(const uint4*)&Ct[r][v * 8];
  }
}

// ---------------------------------------------------------------- edge logits in CSR order
__global__ void k_edge_l(const int* __restrict__ src_csr, const int* __restrict__ dst_csr,
                         const float* __restrict__ edot, const float* __restrict__ s,
                         const float* __restrict__ d, float* __restrict__ lcsr, int e) {
  int i = blockIdx.x * 256 + threadIdx.x;
  if (i >= e) return;
  float l = s[src_csr[i]] + d[dst_csr[i]] + edot[i];
  lcsr[i] = (l > 0.f) ? l : 0.2f * l;
}

// ---------------------------------------------------------------- per-node softmax: lcsr (logits) -> alpha in place
__global__ void k_nodealpha(const int* __restrict__ off, float* __restrict__ lcsr, int n) {
  int node = blockIdx.x * 256 + threadIdx.x;
  if (node >= n) return;
  int e0 = off[node], e1 = off[node + 1];
  if (e0 == e1) return;
  float m = -INFINITY;
  for (int i = e0; i < e1; ++i) m = fmaxf(m, lcsr[i]);
  float den = 0.f;
  for (int i = e0; i < e1; ++i) {
    float ex = __expf(lcsr[i] - m);
    lcsr[i] = ex;
    den += ex;
  }
  float inv = 1.f / (den + 1e-16f);
  for (int i = e0; i < e1; ++i) lcsr[i] *= inv;
}

// ---------------------------------------------------------------- agg gather (alpha precomputed) + fused BN partials
// 8 nodes/block, 32 lanes/node; 4-deep load pipeline; grid-stride;
// per-block partial sum/sumsq -> partials[block][256]
__global__ __launch_bounds__(256) void k_agg128v(
    const int* __restrict__ off, const int* __restrict__ src_csr,
    const float* __restrict__ alpha, const bf16* __restrict__ feat,
    const float* __restrict__ bias, bf16* __restrict__ out,
    float* __restrict__ partials, int n) {
  __shared__ float sm[8][128], sq2[8][128];
  int grp = threadIdx.x >> 5, lane = threadIdx.x & 31;
  float4 b4 = ((const float4*)bias)[lane];
  float s0 = 0.f, s1 = 0.f, s2 = 0.f, s3 = 0.f;
  float q0 = 0.f, q1 = 0.f, q2 = 0.f, q3 = 0.f;
  int stride = gridDim.x * 8;
  for (int node = blockIdx.x * 8 + grp; node < n; node += stride) {
    int e0 = off[node], e1 = off[node + 1];
    float a0 = 0.f, a1 = 0.f, a2 = 0.f, a3 = 0.f;
    int i = e0;
    for (; i + 4 <= e1; i += 4) {
      float al0 = alpha[i], al1 = alpha[i + 1], al2 = alpha[i + 2], al3 = alpha[i + 3];
      uint2 u0 = ((const uint2*)(feat + (size_t)src_csr[i] * 128))[lane];
      uint2 u1 = ((const uint2*)(feat + (size_t)src_csr[i + 1] * 128))[lane];
      uint2 u2 = ((const uint2*)(feat + (size_t)src_csr[i + 2] * 128))[lane];
      uint2 u3 = ((const uint2*)(feat + (size_t)src_csr[i + 3] * 128))[lane];
      a0 += al0 * bflo(u0.x) + al1 * bflo(u1.x) + al2 * bflo(u2.x) + al3 * bflo(u3.x);
      a1 += al0 * bfhi(u0.x) + al1 * bfhi(u1.x) + al2 * bfhi(u2.x) + al3 * bfhi(u3.x);
      a2 += al0 * bflo(u0.y) + al1 * bflo(u1.y) + al2 * bflo(u2.y) + al3 * bflo(u3.y);
      a3 += al0 * bfhi(u0.y) + al1 * bfhi(u1.y) + al2 * bfhi(u2.y) + al3 * bfhi(u3.y);
    }
    for (; i < e1; ++i) {
      float al = alpha[i];
      uint2 u = ((const uint2*)(feat + (size_t)src_csr[i] * 128))[lane];
      a0 += al * bflo(u.x);
      a1 += al * bfhi(u.x);
      a2 += al * bflo(u.y);
      a3 += al * bfhi(u.y);
    }
    a0 += b4.x; a1 += b4.y; a2 += b4.z; a3 += b4.w;
    uint2 o2;
    o2.x = pack2(a0, a1);
    o2.y = pack2(a2, a3);
    ((uint2*)(out + (size_t)node * 128))[lane] = o2;
    s0 += a0; s1 += a1; s2 += a2; s3 += a3;
    q0 += a0 * a0; q1 += a1 * a1; q2 += a2 * a2; q3 += a3 * a3;
  }
  sm[grp][lane * 4] = s0; sm[grp][lane * 4 + 1] = s1;
  sm[grp][lane * 4 + 2] = s2; sm[grp][lane * 4 + 3] = s3;
  sq2[grp][lane * 4] = q0; sq2[grp][lane * 4 + 1] = q1;
  sq2[grp][lane * 4 + 2] = q2; sq2[grp][lane * 4 + 3] = q3;
  __syncthreads();
  if (threadIdx.x < 128) {
    int c = threadIdx.x;
    float a = 0.f, b = 0.f;
#pragma unroll
    for (int g = 0; g < 8; ++g) { a += sm[g][c]; b += sq2[g][c]; }
    partials[(size_t)blockIdx.x * 256 + c] = a;
    partials[(size_t)blockIdx.x * 256 + 128 + c] = b;
  }
}

// ---------------------------------------------------------------- gate feature + s/d
__global__ void k_gfeat(const float* __restrict__ x, const float* __restrict__ W,
                        const float* __restrict__ a_s, const float* __restrict__ a_d,
                        float* __restrict__ gfeat, float* __restrict__ s,
                        float* __restrict__ d, int n) {
  int i = blockIdx.x * 256 + threadIdx.x;
  if (i >= n) return;
  const float* xr = x + (size_t)i * DIN;
  float acc[4] = {0.f, 0.f, 0.f, 0.f};
  for (int k = 0; k < DIN; ++k) {
    float xv = xr[k];
#pragma unroll
    for (int j = 0; j < 4; ++j) acc[j] += xv * W[k * 4 + j];
  }
  float ss = 0.f, dd = 0.f;
#pragma unroll
  for (int j = 0; j < 4; ++j) {
    gfeat[(size_t)i * 4 + j] = acc[j];
    ss += acc[j] * a_s[j];
    dd += acc[j] * a_d[j];
  }
  s[i] = ss; d[i] = dd;
}

// ---------------------------------------------------------------- gate aggregation + channel softmax
__global__ void k_agg4(const int* __restrict__ off, const int* __restrict__ src_csr,
                       const float* __restrict__ lcsr, const float* __restrict__ gfeat,
                       const float* __restrict__ bias, float* __restrict__ gates, int n) {
  int node = blockIdx.x * 256 + threadIdx.x;
  if (node >= n) return;
  int e0 = off[node], e1 = off[node + 1];
  float m = -INFINITY;
  for (int i = e0; i < e1; ++i) m = fmaxf(m, lcsr[i]);
  float den = 0.f;
  for (int i = e0; i < e1; ++i) den += __expf(lcsr[i] - m);
  float inv = 1.f / (den + 1e-16f);
  float4 acc = {0.f, 0.f, 0.f, 0.f};
  for (int i = e0; i < e1; ++i) {
    float a = __expf(lcsr[i] - m) * inv;
    float4 fr = *((const float4*)(gfeat + (size_t)src_csr[i] * 4));
    acc.x += a * fr.x; acc.y += a * fr.y; acc.z += a * fr.z; acc.w += a * fr.w;
  }
  float b0 = bias[0], b1 = bias[1], b2 = bias[2], b3 = bias[3];
  acc.x += b0; acc.y += b1; acc.z += b2; acc.w += b3;
  float mm = fmaxf(fmaxf(acc.x, acc.y), fmaxf(acc.z, acc.w));
  float e0s = __expf(acc.x - mm), e1s = __expf(acc.y - mm);
  float e2s = __expf(acc.z - mm), e3s = __expf(acc.w - mm);
  float is = 1.f / (e0s + e1s + e2s + e3s);
  float4 g4 = {e0s * is, e1s * is, e2s * is, e3s * is};
  *((float4*)(gates + (size_t)node * 4)) = g4;
}

// stage 2: reduce partials -> sums[0..127], sums[128..255]. grid = 16 blocks x 8 ch.
__global__ void k_bnstats_fin(const float* __restrict__ partials, float* __restrict__ sums,
                              int nblk) {
  int t = threadIdx.x;
  int cl = t >> 5, sl = t & 31;
  int ch = blockIdx.x * 8 + cl;
  float a = 0.f, b = 0.f;
  for (int blk = sl; blk < nblk; blk += 32) {
    a += partials[(size_t)blk * 256 + ch];
    b += partials[(size_t)blk * 256 + 128 + ch];
  }
#pragma unroll
  for (int o = 16; o; o >>= 1) { a += __shfl_xor(a, o); b += __shfl_xor(b, o); }
  if (sl == 0) { sums[ch] = a; sums[128 + ch] = b; }
}

// BN stats fp32 (head path, tiny)
__global__ void k_bnstats_f32(const float* __restrict__ x, float* __restrict__ sums,
                              float* __restrict__ sumsq, int n) {
  __shared__ float s1[256], s2[256];
  int c = threadIdx.x & 127, half = threadIdx.x >> 7;
  float a = 0.f, b = 0.f;
  for (int r = blockIdx.x * 2 + half; r < n; r += gridDim.x * 2) {
    float v = x[(size_t)r * 128 + c];
    a += v; b += v * v;
  }
  s1[threadIdx.x] = a; s2[threadIdx.x] = b;
  __syncthreads();
  if (half == 0) {
    atomicAdd(&sums[c], s1[c] + s1[c + 128]);
    atomicAdd(&sumsq[c], s2[c] + s2[c + 128]);
  }
}

// ---------------------------------------------------------------- fused BN2+leaky+gate+pool
__global__ void k_poolexpert(const bf16* __restrict__ x, const float* __restrict__ sums,
                             const float* __restrict__ sumsq, const float* __restrict__ g,
                             const float* __restrict__ bb, const int* __restrict__ batch,
                             const float* __restrict__ gates0, int slot0,
                             const float* __restrict__ gates1, int slot1,
                             float* __restrict__ pooled0, float* __restrict__ pooled1,
                             int n, float invn) {
  int b = blockIdx.x, t = threadIdx.x;
  int lo = 0, hi = n;
  while (lo < hi) { int m = (lo + hi) >> 1; if (batch[m] < b) lo = m + 1; else hi = m; }
  int start = lo;
  lo = start; hi = n;
  while (lo < hi) { int m = (lo + hi) >> 1; if (batch[m] < b + 1) lo = m + 1; else hi = m; }
  int end = lo;
  int c0 = 2 * t, c1 = 2 * t + 1;
  float mu0 = sums[c0] * invn, mu1 = sums[c1] * invn;
  float sc0 = rsqrtf(sumsq[c0] * invn - mu0 * mu0 + 1e-5f) * g[c0];
  float sc1 = rsqrtf(sumsq[c1] * invn - mu1 * mu1 + 1e-5f) * g[c1];
  float sh0 = bb[c0], sh1 = bb[c1];
  float a00 = 0.f, a01 = 0.f, a10 = 0.f, a11 = 0.f;
  for (int r = start; r < end; ++r) {
    unsigned u = ((const unsigned*)(x + (size_t)r * 128))[t];
    float y0 = (bflo(u) - mu0) * sc0 + sh0;
    float y1 = (bfhi(u) - mu1) * sc1 + sh1;
    y0 = (y0 > 0.f) ? y0 : 0.01f * y0;
    y1 = (y1 > 0.f) ? y1 : 0.01f * y1;
    if (slot0 >= 0) {
      float gw = gates0[(size_t)r * 4 + slot0];
      a00 += gw * y0; a01 += gw * y1;
    }
    if (slot1 >= 0) {
      float gw = gates1[(size_t)r * 4 + slot1];
      a10 += gw * y0; a11 += gw * y1;
    }
  }
  if (slot0 >= 0) {
    pooled0[(size_t)b * 128 + c0] += a00;
    pooled0[(size_t)b * 128 + c1] += a01;
  }
  if (slot1 >= 0) {
    pooled1[(size_t)b * 128 + c0] += a10;
    pooled1[(size_t)b * 128 + c1] += a11;
  }
}

// ---------------------------------------------------------------- K^T = (pe@Wk)^T [128][L], V = pe@Wv [L][128]
__global__ void k_kv(const float* __restrict__ pe, const float* __restrict__ Wk,
                     const float* __restrict__ Wv, float* __restrict__ Kt,
                     float* __restrict__ Vout) {
  __shared__ float per[PD];
  int l = blockIdx.x, c = threadIdx.x;
  for (int p = threadIdx.x; p < PD; p += 128) per[p] = pe[(size_t)l * PD + p];
  __syncthreads();
  float ak = 0.f, av = 0.f;
  for (int p = 0; p < PD; ++p) {
    float v = per[p];
    ak += v * Wk[p * 128 + c];
    av += v * Wv[p * 128 + c];
  }
  Kt[(size_t)c * L + l] = ak;
  Vout[(size_t)l * 128 + c] = av;
}

// out[row,:] = in[row,:Kdim] @ W[Kdim,128]
__global__ void k_rowgemm(const float* __restrict__ in, const float* __restrict__ W,
                          float* __restrict__ out, int Kdim) {
  __shared__ float rr[256];
  int row = blockIdx.x, c = threadIdx.x;
  for (int k = threadIdx.x; k < Kdim; k += 128) rr[k] = in[(size_t)row * Kdim + k];
  __syncthreads();
  float acc = 0.f;
  for (int k = 0; k < Kdim; ++k) acc += rr[k] * W[k * 128 + c];
  out[(size_t)row * 128 + c] = acc;
}

// ---------------------------------------------------------------- cross-attention, 4 graphs per block
__global__ void k_attn(const float* __restrict__ Q, const float* __restrict__ Kt,
                       const float* __restrict__ Vm, float* __restrict__ ctx) {
  __shared__ float q[4][128];
  __shared__ float sc[4][L];
  __shared__ float4 red[128];
  __shared__ float4 Mg, Ig;
  int b0 = blockIdx.x * 4, t = threadIdx.x;
#pragma unroll
  for (int g = 0; g < 4; ++g) q[g][t] = Q[(size_t)(b0 + g) * 128 + t];
  __syncthreads();
  float acc[4][4];
#pragma unroll
  for (int g = 0; g < 4; ++g)
#pragma unroll
    for (int j = 0; j < 4; ++j) acc[g][j] = 0.f;
  for (int k = 0; k < 128; ++k) {
    const float* kr = Kt + (size_t)k * L + t;
    float k0 = kr[0], k1 = kr[128], k2 = kr[256], k3 = kr[384];
#pragma unroll
    for (int g = 0; g < 4; ++g) {
      float qv = q[g][k];
      acc[g][0] += qv * k0; acc[g][1] += qv * k1;
      acc[g][2] += qv * k2; acc[g][3] += qv * k3;
    }
  }
  const float scale = 0.08838834764831845f;
  float4 pm;
  {
    float m[4];
#pragma unroll
    for (int g = 0; g < 4; ++g) {
#pragma unroll
      for (int j = 0; j < 4; ++j) {
        acc[g][j] *= scale;
        sc[g][t + j * 128] = acc[g][j];
      }
      m[g] = fmaxf(fmaxf(acc[g][0], acc[g][1]), fmaxf(acc[g][2], acc[g][3]));
    }
    pm = {m[0], m[1], m[2], m[3]};
  }
  red[t] = pm; __syncthreads();
  for (int s = 64; s > 0; s >>= 1) {
    if (t < s) {
      float4 o = red[t + s];
      red[t].x = fmaxf(red[t].x, o.x); red[t].y = fmaxf(red[t].y, o.y);
      red[t].z = fmaxf(red[t].z, o.z); red[t].w = fmaxf(red[t].w, o.w);
    }
    __syncthreads();
  }
  if (t == 0) Mg = red[0];
  __syncthreads();
  float4 M = Mg;
  float4 ps = {0, 0, 0, 0};
#pragma unroll
  for (int g = 0; g < 4; ++g) {
    float mg = (g == 0) ? M.x : (g == 1) ? M.y : (g == 2) ? M.z : M.w;
    float sgsum = 0.f;
#pragma unroll
    for (int j = 0; j < 4; ++j) {
      float e = __expf(acc[g][j] - mg);
      sc[g][t + j * 128] = e;
      sgsum += e;
    }
    if (g == 0) ps.x = sgsum; else if (g == 1) ps.y = sgsum;
    else if (g == 2) ps.z = sgsum; else ps.w = sgsum;
  }
  __syncthreads();
  red[t] = ps; __syncthreads();
  for (int s = 64; s > 0; s >>= 1) {
    if (t < s) {
      float4 o = red[t + s];
      red[t].x += o.x; red[t].y += o.y; red[t].z += o.z; red[t].w += o.w;
    }
    __syncthreads();
  }
  if (t == 0) Ig = {1.f / red[0].x, 1.f / red[0].y, 1.f / red[0].z, 1.f / red[0].w};
  __syncthreads();
  float4 I = Ig;
  float o0 = 0.f, o1 = 0.f, o2 = 0.f, o3 = 0.f;
  for (int l = 0; l < L; ++l) {
    float v = Vm[(size_t)l * 128 + t];
    o0 += sc[0][l] * v; o1 += sc[1][l] * v; o2 += sc[2][l] * v; o3 += sc[3][l] * v;
  }
  ctx[(size_t)(b0 + 0) * 128 + t] = o0 * I.x;
  ctx[(size_t)(b0 + 1) * 128 + t] = o1 * I.y;
  ctx[(size_t)(b0 + 2) * 128 + t] = o2 * I.z;
  ctx[(size_t)(b0 + 3) * 128 + t] = o3 * I.w;
}

// hh = concat(pooled, ctx) @ Wh1 + bh1
__global__ void k_head1(const float* __restrict__ pooled, const float* __restrict__ ctx,
                        const float* __restrict__ Wh1, const float* __restrict__ bh1,
                        float* __restrict__ hh) {
  __shared__ float f[256];
  int b = blockIdx.x, c = threadIdx.x;
  f[c] = pooled[(size_t)b * 128 + c];
  f[c + 128] = ctx[(size_t)b * 128 + c];
  __syncthreads();
  float acc = bh1[c];
  for (int k = 0; k < 256; ++k) acc += f[k] * Wh1[k * 128 + c];
  hh[(size_t)b * 128 + c] = acc;
}

// bn + leaky + final dot with Wh2 -> out[b*2+t]
__global__ void k_head2(const float* __restrict__ hh, const float* __restrict__ sums,
                        const float* __restrict__ sumsq, const float* __restrict__ g,
                        const float* __restrict__ bbn, const float* __restrict__ Wh2,
                        const float* __restrict__ bh2, float* __restrict__ out, int t,
                        float invn) {
  __shared__ float red[2];
  int b = blockIdx.x, c = threadIdx.x;
  float mu = sums[c] * invn;
  float var = sumsq[c] * invn - mu * mu;
  float y = (hh[(size_t)b * 128 + c] - mu) * rsqrtf(var + 1e-5f) * g[c] + bbn[c];
  y = (y > 0.f) ? y : 0.01f * y;
  float p = y * Wh2[c];
  for (int o = 32; o; o >>= 1) p += __shfl_down(p, o);
  if ((threadIdx.x & 63) == 0) red[threadIdx.x >> 6] = p;
  __syncthreads();
  if (threadIdx.x == 0) out[(size_t)b * 2 + t] = red[0] + red[1] + bh2[0];
}

extern "C" void kernel_launch(void* const* d_in, const int* in_sizes, int n_in,
                              void* d_out, int out_size, void* d_ws, size_t ws_size,
                              hipStream_t stream) {
  (void)n_in; (void)ws_size;
  const float* x     = (const float*)d_in[0];
  const int*   eidx  = (const int*)d_in[1];
  const float* eattr = (const float*)d_in[2];
  const int*   batch = (const int*)d_in[3];
  const float* eW1   = (const float*)d_in[4];
  const float* ea_s1 = (const float*)d_in[5];
  const float* ea_d1 = (const float*)d_in[6];
  const float* eWe1  = (const float*)d_in[7];
  const float* ea_e1 = (const float*)d_in[8];
  const float* eb1   = (const float*)d_in[9];
  const float* bn1_g = (const float*)d_in[10];
  const float* bn1_b = (const float*)d_in[11];
  const float* eW2   = (const float*)d_in[12];
  const float* ea_s2 = (const float*)d_in[13];
  const float* ea_d2 = (const float*)d_in[14];
  const float* eWe2  = (const float*)d_in[15];
  const float* ea_e2 = (const float*)d_in[16];
  const float* eb2   = (const float*)d_in[17];
  const float* bn2_g = (const float*)d_in[18];
  const float* bn2_b = (const float*)d_in[19];
  const float* gW    = (const float*)d_in[20];
  const float* ga_s  = (const float*)d_in[21];
  const float* ga_d  = (const float*)d_in[22];
  const float* gWe   = (const float*)d_in[23];
  const float* ga_e  = (const float*)d_in[24];
  const float* gb    = (const float*)d_in[25];
  const float* Wq    = (const float*)d_in[26];
  const float* Wk    = (const float*)d_in[27];
  const float* Wv    = (const float*)d_in[28];
  const float* pe    = (const float*)d_in[29];
  const float* Wh1   = (const float*)d_in[30];
  const float* bh1   = (const float*)d_in[31];
  const float* hbn_g = (const float*)d_in[32];
  const float* hbn_b = (const float*)d_in[33];
  const float* Wh2   = (const float*)d_in[34];
  const float* bh2   = (const float*)d_in[35];
  float* out = (float*)d_out;

  const int n = in_sizes[0] / DIN;    // 200000
  const int e = in_sizes[1] / 2;      // 800000
  const int nb_graphs = out_size / 2; // 4096
  const int* src = eidx;
  const int* dst = eidx + e;

  char* p = (char*)d_ws;
  auto carve = [&](size_t bytes) {
    void* r = (void*)p;
    p += (bytes + 255) & ~(size_t)255;
    return r;
  };
  int* deg       = (int*)carve((size_t)n * 4);
  int* off       = (int*)carve(((size_t)n + 1) * 4);
  int* cursor    = (int*)carve((size_t)n * 4);
  int* eid       = (int*)carve((size_t)e * 4);
  int* bsum      = (int*)carve(4096);
  int* src_csr   = (int*)carve((size_t)e * 4);
  int* dst_csr   = (int*)carve((size_t)e * 4);
  float* edots   = (float*)carve((size_t)14 * e * 4);
  float* weall   = (float*)carve(14 * 16 * 4);
  float* s_arr   = (float*)carve((size_t)n * 4);
  float* d_arr   = (float*)carve((size_t)n * 4);
  float* lcsr    = (float*)carve((size_t)e * 4);
  float* sums    = (float*)carve(256 * 4);
  float* partials = (float*)carve((size_t)NAGG * 256 * 4);
  float* gates0  = (float*)carve((size_t)n * 16);
  float* gates1  = (float*)carve((size_t)n * 16);
  float* gfeat   = (float*)carve((size_t)n * 16);
  float* pooled0 = (float*)carve((size_t)nb_graphs * H * 4);
  float* pooled1 = (float*)carve((size_t)nb_graphs * H * 4);
  float* Ktbuf   = (float*)carve((size_t)L * H * 4);
  float* Vbuf    = (float*)carve((size_t)L * H * 4);
  float* Qbuf    = (float*)carve((size_t)nb_graphs * H * 4);
  float* ctxb    = (float*)carve((size_t)nb_graphs * H * 4);
  float* hhb     = (float*)carve((size_t)nb_graphs * H * 4);
  bf16* featbuf  = (bf16*)carve((size_t)n * H * 2);
  bf16* buf1     = (bf16*)carve((size_t)n * H * 2);
  bf16* xbf      = (bf16*)carve((size_t)n * DIN * 2);
  bf16* Wp1      = (bf16*)carve((size_t)6 * 8192 * 2);
  bf16* Wp2      = (bf16*)carve((size_t)6 * 16384 * 2);

  float invn = 1.0f / n;

  // ---- one-time prep: x->bf16, weight repack
  k_cvt_bf16<<<(n * DIN / 2 + 255) / 256, 256, 0, stream>>>(x, xbf, n * DIN / 2);
  k_wpackall<<<(6 * 8192 + 6 * 16384 + 255) / 256, 256, 0, stream>>>(eW1, eW2, Wp1, Wp2);

  // ---- CSR by dst (reused by all 14 GAT convs)
  k_zero_i32<<<(n + 255) / 256, 256, 0, stream>>>(deg, n);
  k_deg<<<(e + 255) / 256, 256, 0, stream>>>(dst, deg, e);
  int nsb = (n + 511) / 512;
  k_scan1<<<nsb, 512, 0, stream>>>(deg, off, bsum, n);
  k_scan2<<<1, 512, 0, stream>>>(bsum, nsb);
  k_scan3<<<nsb, 512, 0, stream>>>(off, bsum, cursor, n, e);
  k_fill<<<(e + 255) / 256, 256, 0, stream>>>(dst, cursor, eid, e);

  // ---- all 14 edge-weight dots in CSR order
  k_weall<<<1, 256, 0, stream>>>(gWe, ga_e, eWe1, ea_e1, eWe2, ea_e2, weall);
  k_csrprep<<<(e + 255) / 256, 256, 0, stream>>>(eid, src, dst, eattr, weall, src_csr,
                                                 dst_csr, edots, e);

  // ---- gates (2 tasks)
  for (int t = 0; t < 2; ++t) {
    float* gates = t ? gates1 : gates0;
    k_gfeat<<<(n + 255) / 256, 256, 0, stream>>>(x, gW + t * DIN * 4, ga_s + t * 4,
                                                 ga_d + t * 4, gfeat, s_arr, d_arr, n);
    k_edge_l<<<(e + 255) / 256, 256, 0, stream>>>(src_csr, dst_csr, edots + (size_t)t * e,
                                                  s_arr, d_arr, lcsr, e);
    k_agg4<<<(n + 255) / 256, 256, 0, stream>>>(off, src_csr, lcsr, gfeat, gb + t * 4,
                                                gates, n);
  }

  // ---- zero pooled accumulators
  k_zero_f32<<<(nb_graphs * H + 255) / 256, 256, 0, stream>>>(pooled0, nb_graphs * H);
  k_zero_f32<<<(nb_graphs * H + 255) / 256, 256, 0, stream>>>(pooled1, nb_graphs * H);

  // ---- 6 experts (MFMA GEMMs; BN1 fused into layer-2 staging; alpha precomputed; agg fuses BN partials)
  int gblk = (n + 63) / 64;
  for (int i = 0; i < 6; ++i) {
    // layer 1 (DIN -> H)
    k_mfma_gemm<DIN, false><<<gblk, 256, 0, stream>>>(
        xbf, Wp1 + (size_t)i * 8192, ea_s1 + i * H, ea_d1 + i * H, featbuf, s_arr, d_arr,
        n, nullptr, nullptr, nullptr, 0.f);
    k_edge_l<<<(e + 255) / 256, 256, 0, stream>>>(src_csr, dst_csr,
                                                  edots + (size_t)(2 + i) * e, s_arr,
                                                  d_arr, lcsr, e);
    k_nodealpha<<<(n + 255) / 256, 256, 0, stream>>>(off, lcsr, n);
    k_agg128v<<<NAGG, 256, 0, stream>>>(off, src_csr, lcsr, featbuf, eb1 + i * H, buf1,
                                        partials, n);
    k_bnstats_fin<<<16, 256, 0, stream>>>(partials, sums, NAGG);
    // layer 2 (H -> H); BN1 + leaky applied during A staging
    k_mfma_gemm<H, true><<<gblk, 256, 0, stream>>>(
        buf1, Wp2 + (size_t)i * 16384, ea_s2 + i * H, ea_d2 + i * H, featbuf, s_arr,
        d_arr, n, sums, bn1_g + i * H, bn1_b + i * H, invn);
    k_edge_l<<<(e + 255) / 256, 256, 0, stream>>>(src_csr, dst_csr,
                                                  edots + (size_t)(8 + i) * e, s_arr,
                                                  d_arr, lcsr, e);
    k_nodealpha<<<(n + 255) / 256, 256, 0, stream>>>(off, lcsr, n);
    k_agg128v<<<NAGG, 256, 0, stream>>>(off, src_csr, lcsr, featbuf, eb2 + i * H, buf1,
                                        partials, n);
    k_bnstats_fin<<<16, 256, 0, stream>>>(partials, sums, NAGG);
    int s0 = (i < 4) ? i : -1;
    int s1 = (i < 2) ? i : (i >= 4 ? i - 2 : -1);
    k_poolexpert<<<nb_graphs, 64, 0, stream>>>(buf1, sums, sums + 128, bn2_g + i * H,
                                               bn2_b + i * H, batch, gates0, s0, gates1,
                                               s1, pooled0, pooled1, n, invn);
  }

  // ---- heads
  for (int t = 0; t < 2; ++t) {
    const float* pooled = t ? pooled1 : pooled0;
    k_kv<<<L, 128, 0, stream>>>(pe + (size_t)t * L * PD, Wk + t * PD * H, Wv + t * PD * H,
                                Ktbuf, Vbuf);
    k_rowgemm<<<nb_graphs, 128, 0, stream>>>(pooled, Wq + t * H * H, Qbuf, H);
    k_attn<<<nb_graphs / 4, 128, 0, stream>>>(Qbuf, Ktbuf, Vbuf, ctxb);
    k_head1<<<nb_graphs, 128, 0, stream>>>(pooled, ctxb, Wh1 + t * 2 * H * H, bh1 + t * H,
                                           hhb);
    k_zero_f32<<<1, 256, 0, stream>>>(sums, 256);
    k_bnstats_f32<<<64, 256, 0, stream>>>(hhb, sums, sums + 128, nb_graphs);
    k_head2<<<nb_graphs, 128, 0, stream>>>(hhb, sums, sums + 128, hbn_g + t * H,
                                           hbn_b + t * H, Wh2 + t * H, bh2 + t, out, t,
                                           1.0f / nb_graphs);
  }
}